// Round 2
// baseline (14512.047 us; speedup 1.0000x reference)
//
#include <hip/hip_runtime.h>
#include <math.h>

// Problem constants
#define BDIM 4096
#define TLEN 48
#define FEAT 35
#define HID 1024
#define H4 4096
#define KTOT 1152      // 1024 (hh) + 128 (ih, 70 real + 58 zero pad)

#define BH ((size_t)BDIM * HID)

typedef unsigned short u16;
typedef unsigned char u8;
typedef __bf16 bf16x8 __attribute__((ext_vector_type(8)));
typedef float f32x4 __attribute__((ext_vector_type(4)));
typedef u16 u16x8 __attribute__((ext_vector_type(8)));
typedef int v8i __attribute__((ext_vector_type(8)));
typedef int v4i __attribute__((ext_vector_type(4)));

#define SCALE1 0x7F7F7F7F   // E8M0 scale = 1.0 in every byte

__device__ __forceinline__ float b2f(u16 u) {
    union { float f; unsigned i; } v; v.i = ((unsigned)u) << 16; return v.f;
}
__device__ __forceinline__ u16 f2b(float f) {
    union { float f; unsigned i; } v; v.f = f;
    unsigned r = v.i + 0x7FFF + ((v.i >> 16) & 1);
    return (u16)(r >> 16);
}
__device__ __forceinline__ unsigned pk4_fp8(float a, float b, float c, float d) {
    int lo = __builtin_amdgcn_cvt_pk_fp8_f32(a, b, 0, false);
    int hi = __builtin_amdgcn_cvt_pk_fp8_f32(c, d, lo, true);
    return (unsigned)hi;
}
__device__ __forceinline__ u8 f2e4m3(float f) {
    return (u8)(__builtin_amdgcn_cvt_pk_fp8_f32(f, 0.f, 0, false) & 0xFF);
}
__device__ __forceinline__ float sigf(float x) { return __builtin_amdgcn_rcpf(1.f + __expf(-x)); }
__device__ __forceinline__ float tanh_fast(float x) { return 1.f - 2.f * __builtin_amdgcn_rcpf(1.f + __expf(2.f * x)); }

// ---------------- prep kernels ----------------
// Combined fp8 weight matrix W[4096][1152], rows reordered:
// orig n = g*HID + j  ->  new n = (j>>5)*128 + g*32 + (j&31)
__global__ __launch_bounds__(256) void prep_w(const float* __restrict__ W_hh, const float* __restrict__ W_ih,
                                              u8* __restrict__ W) {
    int newn = blockIdx.x;
    int nbk = newn >> 7, rem = newn & 127, g = rem >> 5, jl = rem & 31;
    int orig = g * HID + nbk * 32 + jl;
    u8* dst = W + (size_t)newn * KTOT;
    const float* src = W_hh + (size_t)orig * HID;
    const float* src2 = W_ih + (size_t)orig * (2 * FEAT);
    for (int k4 = threadIdx.x; k4 < KTOT / 4; k4 += 256) {
        int k = k4 * 4;
        float f0, f1, f2, f3;
        if (k < HID) {
            f0 = src[k]; f1 = src[k + 1]; f2 = src[k + 2]; f3 = src[k + 3];
        } else {
            int q = k - HID;
            f0 = (q     < 2 * FEAT) ? src2[q]     : 0.f;
            f1 = (q + 1 < 2 * FEAT) ? src2[q + 1] : 0.f;
            f2 = (q + 2 < 2 * FEAT) ? src2[q + 2] : 0.f;
            f3 = (q + 3 < 2 * FEAT) ? src2[q + 3] : 0.f;
        }
        *(unsigned*)(dst + k) = pk4_fp8(f0, f1, f2, f3);
    }
}

__global__ __launch_bounds__(256) void prep_bias(const float* __restrict__ b_ih, const float* __restrict__ b_hh,
                                                 float* __restrict__ bias_r) {
    int newn = blockIdx.x * 256 + threadIdx.x;
    int nbk = newn >> 7, rem = newn & 127, g = rem >> 5, jl = rem & 31;
    int orig = g * HID + nbk * 32 + jl;
    bias_r[newn] = b_ih[orig] + b_hh[orig];
}

// tdWtb[j][f] bf16, [1024][64], f>=35 zero.
__global__ __launch_bounds__(256) void prep_tdwtb(const float* __restrict__ td_W, u16* __restrict__ tdWtb) {
    int idx = blockIdx.x * 256 + threadIdx.x;
    int row = idx >> 6, f = idx & 63;
    tdWtb[idx] = (f < FEAT) ? f2b(td_W[(size_t)row * FEAT + f]) : (u16)0;
}

// regW8[f][k] fp8, [48][1024], f>=35 zero.
__global__ __launch_bounds__(256) void prep_regw8(const float* __restrict__ reg_W, u8* __restrict__ regW8) {
    int row = blockIdx.x;           // 48
    int k = threadIdx.x * 4;        // 1024
    float f0 = 0.f, f1 = 0.f, f2 = 0.f, f3 = 0.f;
    if (row < FEAT) {
        const float* s = reg_W + (size_t)row * HID + k;
        f0 = s[0]; f1 = s[1]; f2 = s[2]; f3 = s[3];
    }
    *(unsigned*)(regW8 + (size_t)row * 1024 + k) = pk4_fp8(f0, f1, f2, f3);
}

// ---------------- stepR: regression + x_c + loss + gamma(t+1) ----------------
__global__ __launch_bounds__(256) void stepR(const float* __restrict__ values, const float* __restrict__ masks,
                                             const float* __restrict__ deltas, const u16* __restrict__ tdWtb,
                                             const float* __restrict__ td_b, const u8* __restrict__ regW8,
                                             const float* __restrict__ reg_b, u8* __restrict__ X,
                                             u16* __restrict__ gbuf, float* __restrict__ imput,
                                             float* __restrict__ xnum_part, float* __restrict__ xden_part,
                                             int t, int gflag) {
    __shared__ u16 d_sh[16 * 64];          // bf16 d(t+1), 16B-chunk XOR swizzled per row
    __shared__ float x_sh[16 * 35], m_sh[16 * 35];
    __shared__ float xhp[4][16][49];       // per-wave regression partials (padded)
    __shared__ float redbuf[8];

    int tid = threadIdx.x;
    int wave = tid >> 6, lane = tid & 63;
    int cl = lane & 15, quad = lane >> 4;
    int b0 = blockIdx.x * 16;

    for (int i = tid; i < 16 * 35; i += 256) {
        int b = i / 35, f = i - b * 35;
        size_t g = ((size_t)(b0 + b) * TLEN + t) * FEAT + f;
        x_sh[i] = values[g];
        m_sh[i] = masks[g];
    }
    if (gflag && tid < 128) {
        int b = tid >> 3, cch = tid & 7;
        const float* drow = deltas + ((size_t)(b0 + b) * TLEN + (t + 1)) * FEAT;
        u16x8 tv;
        #pragma unroll
        for (int k = 0; k < 8; ++k) {
            int f = cch * 8 + k;
            tv[k] = (f < FEAT) ? f2b(drow[f]) : (u16)0;
        }
        int csw = cch ^ (b & 7);
        *(u16x8*)(d_sh + b * 64 + csw * 8) = tv;
    }
    __syncthreads();

    // ---- regression via MX-fp8 MFMA (K split: wave covers K [wave*256, +256)) ----
    f32x4 racc[3];
    #pragma unroll
    for (int nt = 0; nt < 3; ++nt) racc[nt] = (f32x4){0.f, 0.f, 0.f, 0.f};
    const u8* xrow = X + (size_t)(b0 + cl) * KTOT + wave * 256;
    #pragma unroll
    for (int it = 0; it < 2; ++it) {
        v8i av = *(const v8i*)(xrow + it * 128 + quad * 32);
        #pragma unroll
        for (int nt = 0; nt < 3; ++nt) {
            v8i bvv = *(const v8i*)(regW8 + (size_t)(nt * 16 + cl) * 1024 + wave * 256 + it * 128 + quad * 32);
            racc[nt] = __builtin_amdgcn_mfma_scale_f32_16x16x128_f8f6f4(
                av, bvv, racc[nt], 0, 0, 0, SCALE1, 0, SCALE1);
        }
    }
    #pragma unroll
    for (int nt = 0; nt < 3; ++nt)
        #pragma unroll
        for (int r = 0; r < 4; ++r)
            xhp[wave][quad * 4 + r][nt * 16 + cl] = racc[nt][r];

    // ---- gamma MFMA (bf16): wave covers j-tiles [wave*16, wave*16+16) ----
    if (gflag) {
        int swc0 = quad ^ (cl & 7);
        int swc1 = (4 + quad) ^ (cl & 7);
        bf16x8 a0 = *(const bf16x8*)(d_sh + cl * 64 + swc0 * 8);
        bf16x8 a1 = *(const bf16x8*)(d_sh + cl * 64 + swc1 * 8);
        #pragma unroll 4
        for (int jt2 = 0; jt2 < 16; ++jt2) {
            int jt = wave * 16 + jt2;
            const u16* tw = tdWtb + (size_t)(jt * 16 + cl) * 64;
            bf16x8 b0v = *(const bf16x8*)(tw + quad * 8);
            bf16x8 b1v = *(const bf16x8*)(tw + 32 + quad * 8);
            f32x4 g4 = (f32x4){0.f, 0.f, 0.f, 0.f};
            g4 = __builtin_amdgcn_mfma_f32_16x16x32_bf16(a0, b0v, g4, 0, 0, 0);
            g4 = __builtin_amdgcn_mfma_f32_16x16x32_bf16(a1, b1v, g4, 0, 0, 0);
            float4 tb = *(const float4*)(td_b + jt * 16 + quad * 4);
            float tbv[4] = {tb.x, tb.y, tb.z, tb.w};
            #pragma unroll
            for (int r = 0; r < 4; ++r) {
                u16 gam = f2b(__expf(-fmaxf(g4[r] + tbv[r], 0.f)));
                gbuf[(size_t)(b0 + quad * 4 + r) * HID + jt * 16 + cl] = gam;
            }
        }
    }
    __syncthreads();

    // ---- epilogue: x_c, imputations, X tail (fp8), loss partials ----
    float lossN = 0.f, lossD = 0.f;
    for (int i = tid; i < 16 * 35; i += 256) {
        int b = i / 35, f = i - b * 35;
        float xh = xhp[0][b][f] + xhp[1][b][f] + xhp[2][b][f] + xhp[3][b][f] + reg_b[f];
        float xv = x_sh[i], mv = m_sh[i];
        float xc = mv * xv + (1.f - mv) * xh;
        imput[((size_t)(b0 + b) * TLEN + t) * FEAT + f] = xc;
        u8* Xr = X + (size_t)(b0 + b) * KTOT;
        Xr[HID + f] = f2e4m3(xc);
        Xr[HID + FEAT + f] = f2e4m3(mv);
        lossN += fabsf(xv - xh) * mv;
        lossD += mv;
    }
    for (int i = tid; i < 16 * 58; i += 256) {
        int b = i / 58, k = i - b * 58;
        X[(size_t)(b0 + b) * KTOT + HID + 2 * FEAT + k] = 0;
    }
    #pragma unroll
    for (int off = 32; off; off >>= 1) {
        lossN += __shfl_down(lossN, off);
        lossD += __shfl_down(lossD, off);
    }
    if (lane == 0) { redbuf[wave] = lossN; redbuf[4 + wave] = lossD; }
    __syncthreads();
    if (tid == 0) {
        xnum_part[t * 256 + blockIdx.x] = redbuf[0] + redbuf[1] + redbuf[2] + redbuf[3];
        xden_part[t * 256 + blockIdx.x] = redbuf[4] + redbuf[5] + redbuf[6] + redbuf[7];
    }
}

// ---------------- stepB: MX-fp8 MFMA gates GEMM + fused LSTM cell ----------------
// 256x256 tile, 8 waves (4M x 2N), BK=128, double-buffered LDS (128 KiB), 1 block/CU.
// Per K-step: 4 phases of {ds_read subtile || 2x global_load_lds prefetch -> barrier ->
// lgkmcnt(0) -> setprio(1) 8 MFMA setprio(0) -> barrier}; single vmcnt(0) AFTER all MFMAs
// of the step (T3+T4: load latency hidden under MFMA). T2 chunk-XOR swizzle as before.
// Register budget: 8 waves = 2 waves/SIMD hard -> 256 unified regs/wave. R0's
// __launch_bounds__(512,2) capped at 128 -> acc spilled to scratch (453MB FETCH /
// 338MB WRITE of scratch traffic, 296us). Set backend attrs directly for the 256 cap.
#define LDB2(p) { \
        v4i lo0 = *(const v4i*)(br + (2*(p)) * (16*128) + swlo); \
        v4i hi0 = *(const v4i*)(br + (2*(p)) * (16*128) + swhi); \
        bv[0] = (v8i){lo0[0], lo0[1], lo0[2], lo0[3], hi0[0], hi0[1], hi0[2], hi0[3]}; \
        v4i lo1 = *(const v4i*)(br + (2*(p)+1) * (16*128) + swlo); \
        v4i hi1 = *(const v4i*)(br + (2*(p)+1) * (16*128) + swhi); \
        bv[1] = (v8i){lo1[0], lo1[1], lo1[2], lo1[3], hi1[0], hi1[1], hi1[2], hi1[3]}; \
    }

#define STG(gptr, lds, it) \
    __builtin_amdgcn_global_load_lds((const __attribute__((address_space(1))) void*)((gptr) + (size_t)(it) * 8 * KTOT + kb), \
                                     (__attribute__((address_space(3))) void*)((lds) + (it) * 1024), 16, 0, 0)

#define MFMA8(p) \
    __builtin_amdgcn_s_setprio(1); \
    _Pragma("unroll") \
    for (int mi = 0; mi < 4; ++mi) { \
        acc[mi][2*(p)]   = __builtin_amdgcn_mfma_scale_f32_16x16x128_f8f6f4(av[mi], bv[0], acc[mi][2*(p)],   0, 0, 0, SCALE1, 0, SCALE1); \
        acc[mi][2*(p)+1] = __builtin_amdgcn_mfma_scale_f32_16x16x128_f8f6f4(av[mi], bv[1], acc[mi][2*(p)+1], 0, 0, 0, SCALE1, 0, SCALE1); \
    } \
    __builtin_amdgcn_s_setprio(0);

#define WAIT_LGKM asm volatile("s_waitcnt lgkmcnt(0)" ::: "memory"); __builtin_amdgcn_sched_barrier(0)
#define WAIT_VM   asm volatile("s_waitcnt vmcnt(0)" ::: "memory");   __builtin_amdgcn_sched_barrier(0)

__global__ __attribute__((amdgpu_flat_work_group_size(512, 512), amdgpu_waves_per_eu(2)))
void stepB(const u8* __restrict__ X, const u8* __restrict__ W,
           const float* __restrict__ bias_r, const u16* __restrict__ gbuf,
           u16* __restrict__ c, u8* __restrict__ Xn,
           u16* __restrict__ h, int last) {
    __shared__ u8 As[2][256 * 128];
    __shared__ u8 Bs[2][256 * 128];
    int bid = blockIdx.x;
    int xcd = bid & 7, gidx = bid >> 3;
    int mb = (xcd >> 1) * 4 + (gidx >> 3);   // [0,16)  (4 mb x 8 nb per XCD -> 3.5MB L2 set)
    int nb = (xcd & 1) * 8 + (gidx & 7);     // [0,16)
    int tid = threadIdx.x;
    int wave = tid >> 6, lane = tid & 63;
    int wm = wave >> 1, wn = wave & 1;       // waves: 4M x 2N; wave tile 64M x 128N
    int lrow = lane >> 3;                    // 0..7 row within 8-row staging group
    int gchunk = (lane & 7) ^ lrow;          // swizzled global 16B-chunk to fetch
    int cl = lane & 15, quad = lane >> 4;
    int c7 = cl & 7;
    int swlo = ((2 * quad) ^ c7) << 4;
    int swhi = ((2 * quad + 1) ^ c7) << 4;

    const u8* gA = X + (size_t)(mb * 256 + wave * 32 + lrow) * KTOT + gchunk * 16;
    const u8* gB = W + (size_t)(nb * 256 + wave * 32 + lrow) * KTOT + gchunk * 16;
    u8* lA = (u8*)&As[0][0] + wave * (32 * 128);   // + it*1024 rows, + buf*32768
    u8* lB = (u8*)&Bs[0][0] + wave * (32 * 128);

    f32x4 acc[4][8];
    #pragma unroll
    for (int mi = 0; mi < 4; ++mi)
        #pragma unroll
        for (int ni = 0; ni < 8; ++ni) acc[mi][ni] = (f32x4){0.f, 0.f, 0.f, 0.f};

    // prologue: stage K-step 0 into buffer 0
    {
        int kb = 0;
        #pragma unroll
        for (int it = 0; it < 4; ++it) { STG(gA, lA, it); STG(gB, lB, it); }
    }
    WAIT_VM;
    __builtin_amdgcn_s_barrier();

    for (int kt = 0; kt < 9; ++kt) {
        int cur = kt & 1, nxt = cur ^ 1;
        int kb = (kt + 1) * 128;
        const u8* ar = &As[cur][(wm * 64 + cl) * 128];
        const u8* br = &Bs[cur][(wn * 128 + cl) * 128];
        u8* sA = lA + nxt * (256 * 128);
        u8* sB = lB + nxt * (256 * 128);
        bool st = (kt != 8);

        v8i av[4], bv[2];
        // ---- phase 0: av[0..3] + bv[0..1]; prefetch A rows 0..15 ----
        #pragma unroll
        for (int mi = 0; mi < 4; ++mi) {
            v4i lo = *(const v4i*)(ar + mi * (16 * 128) + swlo);
            v4i hi = *(const v4i*)(ar + mi * (16 * 128) + swhi);
            av[mi] = (v8i){lo[0], lo[1], lo[2], lo[3], hi[0], hi[1], hi[2], hi[3]};
        }
        LDB2(0);
        if (st) { STG(gA, sA, 0); STG(gA, sA, 1); }
        __builtin_amdgcn_s_barrier();
        WAIT_LGKM;
        MFMA8(0);
        __builtin_amdgcn_s_barrier();

        // ---- phase 1: bv[2..3]; prefetch A rows 16..31 ----
        LDB2(1);
        if (st) { STG(gA, sA, 2); STG(gA, sA, 3); }
        __builtin_amdgcn_s_barrier();
        WAIT_LGKM;
        MFMA8(1);
        __builtin_amdgcn_s_barrier();

        // ---- phase 2: bv[4..5]; prefetch B rows 0..15 ----
        LDB2(2);
        if (st) { STG(gB, sB, 0); STG(gB, sB, 1); }
        __builtin_amdgcn_s_barrier();
        WAIT_LGKM;
        MFMA8(2);
        __builtin_amdgcn_s_barrier();

        // ---- phase 3: bv[6..7]; prefetch B rows 16..31; boundary vmcnt AFTER MFMA ----
        LDB2(3);
        if (st) { STG(gB, sB, 2); STG(gB, sB, 3); }
        __builtin_amdgcn_s_barrier();
        WAIT_LGKM;
        MFMA8(3);
        WAIT_VM;
        __builtin_amdgcn_s_barrier();
    }

    // fused LSTM epilogue; for t<47 write X_hdec(t+1) = h*gamma(t+1) in fp8, for t=47 write h bf16.
    int group = nb * 2 + wn;                  // 128-wide gate-block index [0,32)
    #pragma unroll
    for (int mi = 0; mi < 4; ++mi) {
        #pragma unroll
        for (int r = 0; r < 4; ++r) {
            int b = mb * 256 + wm * 64 + mi * 16 + quad * 4 + r;
            #pragma unroll
            for (int jh = 0; jh < 2; ++jh) {
                int jl = jh * 16 + cl;
                int j = group * 32 + jl;
                float iv = acc[mi][jh + 0][r] + bias_r[group * 128 + jl];
                float fv = acc[mi][jh + 2][r] + bias_r[group * 128 + 32 + jl];
                float gg = acc[mi][jh + 4][r] + bias_r[group * 128 + 64 + jl];
                float ov = acc[mi][jh + 6][r] + bias_r[group * 128 + 96 + jl];
                iv = sigf(iv); fv = sigf(fv); ov = sigf(ov); gg = tanh_fast(gg);
                size_t idx = (size_t)b * HID + j;
                float cn = fv * b2f(c[idx]) + iv * gg;
                c[idx] = f2b(cn);
                float hn = ov * tanh_fast(cn);
                if (last) {
                    h[idx] = f2b(hn);
                } else {
                    Xn[(size_t)b * KTOT + j] = f2e4m3(hn * b2f(gbuf[idx]));
                }
            }
        }
    }
}

// ---------------- final kernels (atomic-free) ----------------
__global__ __launch_bounds__(256) void finalY(const u16* __restrict__ h, const float* __restrict__ out_W,
                                              const float* __restrict__ out_b, const float* __restrict__ labels,
                                              const float* __restrict__ is_train, float* __restrict__ preds,
                                              float* __restrict__ bce_part, float* __restrict__ it_part) {
    __shared__ float wbuf[8];
    int tid = threadIdx.x;
    int wave = tid >> 6, lane = tid & 63;
    int cl = lane & 15, quad = lane >> 4;
    int b = blockIdx.x * 16 + wave * 4 + quad;
    const u16x8* hp = (const u16x8*)(h + (size_t)b * HID + cl * 64);
    const float4* wp = (const float4*)(out_W + cl * 64);
    float s = 0.f;
    #pragma unroll
    for (int i = 0; i < 8; ++i) {
        u16x8 hv = hp[i];
        float4 wa = wp[2 * i], wb = wp[2 * i + 1];
        s += b2f(hv[0]) * wa.x + b2f(hv[1]) * wa.y + b2f(hv[2]) * wa.z + b2f(hv[3]) * wa.w
           + b2f(hv[4]) * wb.x + b2f(hv[5]) * wb.y + b2f(hv[6]) * wb.z + b2f(hv[7]) * wb.w;
    }
    s += __shfl_down(s, 8, 16);
    s += __shfl_down(s, 4, 16);
    s += __shfl_down(s, 2, 16);
    s += __shfl_down(s, 1, 16);
    float v1 = 0.f, v2 = 0.f;
    if (cl == 0) {
        float y = s + out_b[0];
        preds[b] = 1.f / (1.f + expf(-y));
        float lab = labels[b], it = is_train[b];
        float mv = fmaxf(-y, 0.f);
        float bce = y - y * lab + mv + logf(expf(-mv) + expf(-y - mv));
        v1 = bce * it; v2 = it;
    }
    v1 += __shfl_xor(v1, 16); v2 += __shfl_xor(v2, 16);
    v1 += __shfl_xor(v1, 32); v2 += __shfl_xor(v2, 32);
    if (lane == 0) { wbuf[wave] = v1; wbuf[4 + wave] = v2; }
    __syncthreads();
    if (tid == 0) {
        bce_part[blockIdx.x] = wbuf[0] + wbuf[1] + wbuf[2] + wbuf[3];
        it_part[blockIdx.x]  = wbuf[4] + wbuf[5] + wbuf[6] + wbuf[7];
    }
}

__global__ __launch_bounds__(256) void finalZ(const float* __restrict__ xnum, const float* __restrict__ xden,
                                              const float* __restrict__ bce_part, const float* __restrict__ it_part,
                                              float* __restrict__ out0) {
    __shared__ float wbuf[12];
    int tid = threadIdx.x, wave = tid >> 6, lane = tid & 63;
    float bs = bce_part[tid], is = it_part[tid];
    #pragma unroll
    for (int off = 32; off; off >>= 1) { bs += __shfl_down(bs, off); is += __shfl_down(is, off); }
    float xl = 0.f;
    for (int t = wave; t < TLEN; t += 4) {
        float n = 0.f, d = 0.f;
        #pragma unroll
        for (int i = 0; i < 4; ++i) { n += xnum[t * 256 + lane + i * 64]; d += xden[t * 256 + lane + i * 64]; }
        #pragma unroll
        for (int off = 32; off; off >>= 1) { n += __shfl_down(n, off); d += __shfl_down(d, off); }
        if (lane == 0) xl += n / (d + 1e-5f);
    }
    if (lane == 0) { wbuf[wave] = xl; wbuf[4 + wave] = bs; wbuf[8 + wave] = is; }
    __syncthreads();
    if (tid == 0) {
        float XL = wbuf[0] + wbuf[1] + wbuf[2] + wbuf[3];
        float BS = wbuf[4] + wbuf[5] + wbuf[6] + wbuf[7];
        float IS = wbuf[8] + wbuf[9] + wbuf[10] + wbuf[11];
        out0[0] = 0.3f * XL + BS / (IS + 1e-5f);
    }
}

// ---------------- launch ----------------
extern "C" void kernel_launch(void* const* d_in, const int* in_sizes, int n_in,
                              void* d_out, int out_size, void* d_ws, size_t ws_size,
                              hipStream_t stream) {
    const float* values   = (const float*)d_in[0];
    const float* masks    = (const float*)d_in[1];
    const float* deltas   = (const float*)d_in[2];
    const float* labels   = (const float*)d_in[3];
    const float* is_train = (const float*)d_in[4];
    const float* td_W     = (const float*)d_in[5];
    const float* td_b     = (const float*)d_in[6];
    const float* W_ih     = (const float*)d_in[7];
    const float* W_hh     = (const float*)d_in[8];
    const float* b_ih     = (const float*)d_in[9];
    const float* b_hh     = (const float*)d_in[10];
    const float* reg_W    = (const float*)d_in[11];
    const float* reg_b    = (const float*)d_in[12];
    const float* out_W    = (const float*)d_in[13];
    const float* out_b    = (const float*)d_in[14];

    float* out = (float*)d_out;

    // workspace (bytes): c bf16[BH] | h bf16[BH] | gbuf bf16[BH] | Xa u8[B*KTOT] | Xb u8[B*KTOT]
    //                    | W8 u8[H4*KTOT] | bias f32[H4] | tdWtb bf16[64K] | regW8 u8[48*1024] | parts
    u16*   c      = (u16*)d_ws;
    u16*   h      = c + BH;
    u16*   gbuf   = h + BH;
    u8*    Xa     = (u8*)(gbuf + BH);
    u8*    Xb     = Xa + (size_t)BDIM * KTOT;
    u8*    W8     = Xb + (size_t)BDIM * KTOT;
    float* bias_r = (float*)(W8 + (size_t)H4 * KTOT);
    u16*   tdWtb  = (u16*)(bias_r + H4);
    u8*    regW8  = (u8*)(tdWtb + 1024 * 64);
    float* xnum_part = (float*)(regW8 + 48 * 1024);
    float* xden_part = xnum_part + TLEN * 256;
    float* bce_part  = xden_part + TLEN * 256;
    float* it_part   = bce_part + 256;

    hipMemsetAsync(c, 0, BH * sizeof(u16), stream);                 // c = 0
    hipMemsetAsync(Xa, 0, (size_t)BDIM * KTOT, stream);             // X_hdec(0) = 0

    prep_w<<<H4, 256, 0, stream>>>(W_hh, W_ih, W8);
    prep_bias<<<H4 / 256, 256, 0, stream>>>(b_ih, b_hh, bias_r);
    prep_tdwtb<<<256, 256, 0, stream>>>(td_W, tdWtb);
    prep_regw8<<<48, 256, 0, stream>>>(reg_W, regW8);

    float* imput = out + 1 + BDIM;
    for (int t = 0; t < TLEN; t++) {
        u8* cur = (t & 1) ? Xb : Xa;
        u8* nxt = (t & 1) ? Xa : Xb;
        stepR<<<BDIM / 16, 256, 0, stream>>>(values, masks, deltas, tdWtb, td_b, regW8, reg_b,
                                             cur, gbuf, imput, xnum_part, xden_part, t, t < TLEN - 1);
        stepB<<<256, 512, 0, stream>>>(cur, W8, bias_r, gbuf, c, nxt, h, t == TLEN - 1);
    }
    finalY<<<BDIM / 16, 256, 0, stream>>>(h, out_W, out_b, labels, is_train, out + 1, bce_part, it_part);
    finalZ<<<1, 256, 0, stream>>>(xnum_part, xden_part, bce_part, it_part, out);
}

// Round 3
// 13588.312 us; speedup vs baseline: 1.0680x; 1.0680x over previous
//
#include <hip/hip_runtime.h>
#include <math.h>

// Problem constants
#define BDIM 4096
#define TLEN 48
#define FEAT 35
#define HID 1024
#define H4 4096
#define KTOT 1152      // 1024 (hh) + 128 (ih, 70 real + 58 zero pad)

#define BH ((size_t)BDIM * HID)

typedef unsigned short u16;
typedef unsigned char u8;
typedef __bf16 bf16x8 __attribute__((ext_vector_type(8)));
typedef float f32x4 __attribute__((ext_vector_type(4)));
typedef u16 u16x8 __attribute__((ext_vector_type(8)));
typedef int v8i __attribute__((ext_vector_type(8)));
typedef int v4i __attribute__((ext_vector_type(4)));

#define SCALE1 0x7F7F7F7F   // E8M0 scale = 1.0 in every byte

__device__ __forceinline__ float b2f(u16 u) {
    union { float f; unsigned i; } v; v.i = ((unsigned)u) << 16; return v.f;
}
__device__ __forceinline__ u16 f2b(float f) {
    union { float f; unsigned i; } v; v.f = f;
    unsigned r = v.i + 0x7FFF + ((v.i >> 16) & 1);
    return (u16)(r >> 16);
}
__device__ __forceinline__ unsigned pk4_fp8(float a, float b, float c, float d) {
    int lo = __builtin_amdgcn_cvt_pk_fp8_f32(a, b, 0, false);
    int hi = __builtin_amdgcn_cvt_pk_fp8_f32(c, d, lo, true);
    return (unsigned)hi;
}
__device__ __forceinline__ u8 f2e4m3(float f) {
    return (u8)(__builtin_amdgcn_cvt_pk_fp8_f32(f, 0.f, 0, false) & 0xFF);
}
__device__ __forceinline__ float sigf(float x) { return __builtin_amdgcn_rcpf(1.f + __expf(-x)); }
__device__ __forceinline__ float tanh_fast(float x) { return 1.f - 2.f * __builtin_amdgcn_rcpf(1.f + __expf(2.f * x)); }

// ---------------- prep kernels ----------------
// Combined fp8 weight matrix W[4096][1152], rows reordered:
// orig n = g*HID + j  ->  new n = (j>>5)*128 + g*32 + (j&31)
__global__ __launch_bounds__(256) void prep_w(const float* __restrict__ W_hh, const float* __restrict__ W_ih,
                                              u8* __restrict__ W) {
    int newn = blockIdx.x;
    int nbk = newn >> 7, rem = newn & 127, g = rem >> 5, jl = rem & 31;
    int orig = g * HID + nbk * 32 + jl;
    u8* dst = W + (size_t)newn * KTOT;
    const float* src = W_hh + (size_t)orig * HID;
    const float* src2 = W_ih + (size_t)orig * (2 * FEAT);
    for (int k4 = threadIdx.x; k4 < KTOT / 4; k4 += 256) {
        int k = k4 * 4;
        float f0, f1, f2, f3;
        if (k < HID) {
            f0 = src[k]; f1 = src[k + 1]; f2 = src[k + 2]; f3 = src[k + 3];
        } else {
            int q = k - HID;
            f0 = (q     < 2 * FEAT) ? src2[q]     : 0.f;
            f1 = (q + 1 < 2 * FEAT) ? src2[q + 1] : 0.f;
            f2 = (q + 2 < 2 * FEAT) ? src2[q + 2] : 0.f;
            f3 = (q + 3 < 2 * FEAT) ? src2[q + 3] : 0.f;
        }
        *(unsigned*)(dst + k) = pk4_fp8(f0, f1, f2, f3);
    }
}

__global__ __launch_bounds__(256) void prep_bias(const float* __restrict__ b_ih, const float* __restrict__ b_hh,
                                                 float* __restrict__ bias_r) {
    int newn = blockIdx.x * 256 + threadIdx.x;
    int nbk = newn >> 7, rem = newn & 127, g = rem >> 5, jl = rem & 31;
    int orig = g * HID + nbk * 32 + jl;
    bias_r[newn] = b_ih[orig] + b_hh[orig];
}

// tdWtb[j][f] bf16, [1024][64], f>=35 zero.
__global__ __launch_bounds__(256) void prep_tdwtb(const float* __restrict__ td_W, u16* __restrict__ tdWtb) {
    int idx = blockIdx.x * 256 + threadIdx.x;
    int row = idx >> 6, f = idx & 63;
    tdWtb[idx] = (f < FEAT) ? f2b(td_W[(size_t)row * FEAT + f]) : (u16)0;
}

// regW8[f][k] fp8, [48][1024], f>=35 zero.
__global__ __launch_bounds__(256) void prep_regw8(const float* __restrict__ reg_W, u8* __restrict__ regW8) {
    int row = blockIdx.x;           // 48
    int k = threadIdx.x * 4;        // 1024
    float f0 = 0.f, f1 = 0.f, f2 = 0.f, f3 = 0.f;
    if (row < FEAT) {
        const float* s = reg_W + (size_t)row * HID + k;
        f0 = s[0]; f1 = s[1]; f2 = s[2]; f3 = s[3];
    }
    *(unsigned*)(regW8 + (size_t)row * 1024 + k) = pk4_fp8(f0, f1, f2, f3);
}

// ---------------- stepR: regression + x_c + loss + gamma(t+1) ----------------
__global__ __launch_bounds__(256) void stepR(const float* __restrict__ values, const float* __restrict__ masks,
                                             const float* __restrict__ deltas, const u16* __restrict__ tdWtb,
                                             const float* __restrict__ td_b, const u8* __restrict__ regW8,
                                             const float* __restrict__ reg_b, u8* __restrict__ X,
                                             u16* __restrict__ gbuf, float* __restrict__ imput,
                                             float* __restrict__ xnum_part, float* __restrict__ xden_part,
                                             int t, int gflag) {
    __shared__ u16 d_sh[16 * 64];          // bf16 d(t+1), 16B-chunk XOR swizzled per row
    __shared__ float x_sh[16 * 35], m_sh[16 * 35];
    __shared__ float xhp[4][16][49];       // per-wave regression partials (padded)
    __shared__ float redbuf[8];

    int tid = threadIdx.x;
    int wave = tid >> 6, lane = tid & 63;
    int cl = lane & 15, quad = lane >> 4;
    int b0 = blockIdx.x * 16;

    for (int i = tid; i < 16 * 35; i += 256) {
        int b = i / 35, f = i - b * 35;
        size_t g = ((size_t)(b0 + b) * TLEN + t) * FEAT + f;
        x_sh[i] = values[g];
        m_sh[i] = masks[g];
    }
    if (gflag && tid < 128) {
        int b = tid >> 3, cch = tid & 7;
        const float* drow = deltas + ((size_t)(b0 + b) * TLEN + (t + 1)) * FEAT;
        u16x8 tv;
        #pragma unroll
        for (int k = 0; k < 8; ++k) {
            int f = cch * 8 + k;
            tv[k] = (f < FEAT) ? f2b(drow[f]) : (u16)0;
        }
        int csw = cch ^ (b & 7);
        *(u16x8*)(d_sh + b * 64 + csw * 8) = tv;
    }
    __syncthreads();

    // ---- regression via MX-fp8 MFMA (K split: wave covers K [wave*256, +256)) ----
    f32x4 racc[3];
    #pragma unroll
    for (int nt = 0; nt < 3; ++nt) racc[nt] = (f32x4){0.f, 0.f, 0.f, 0.f};
    const u8* xrow = X + (size_t)(b0 + cl) * KTOT + wave * 256;
    #pragma unroll
    for (int it = 0; it < 2; ++it) {
        v8i av = *(const v8i*)(xrow + it * 128 + quad * 32);
        #pragma unroll
        for (int nt = 0; nt < 3; ++nt) {
            v8i bvv = *(const v8i*)(regW8 + (size_t)(nt * 16 + cl) * 1024 + wave * 256 + it * 128 + quad * 32);
            racc[nt] = __builtin_amdgcn_mfma_scale_f32_16x16x128_f8f6f4(
                av, bvv, racc[nt], 0, 0, 0, SCALE1, 0, SCALE1);
        }
    }
    #pragma unroll
    for (int nt = 0; nt < 3; ++nt)
        #pragma unroll
        for (int r = 0; r < 4; ++r)
            xhp[wave][quad * 4 + r][nt * 16 + cl] = racc[nt][r];

    // ---- gamma MFMA (bf16): wave covers j-tiles [wave*16, wave*16+16) ----
    if (gflag) {
        int swc0 = quad ^ (cl & 7);
        int swc1 = (4 + quad) ^ (cl & 7);
        bf16x8 a0 = *(const bf16x8*)(d_sh + cl * 64 + swc0 * 8);
        bf16x8 a1 = *(const bf16x8*)(d_sh + cl * 64 + swc1 * 8);
        #pragma unroll 4
        for (int jt2 = 0; jt2 < 16; ++jt2) {
            int jt = wave * 16 + jt2;
            const u16* tw = tdWtb + (size_t)(jt * 16 + cl) * 64;
            bf16x8 b0v = *(const bf16x8*)(tw + quad * 8);
            bf16x8 b1v = *(const bf16x8*)(tw + 32 + quad * 8);
            f32x4 g4 = (f32x4){0.f, 0.f, 0.f, 0.f};
            g4 = __builtin_amdgcn_mfma_f32_16x16x32_bf16(a0, b0v, g4, 0, 0, 0);
            g4 = __builtin_amdgcn_mfma_f32_16x16x32_bf16(a1, b1v, g4, 0, 0, 0);
            float4 tb = *(const float4*)(td_b + jt * 16 + quad * 4);
            float tbv[4] = {tb.x, tb.y, tb.z, tb.w};
            #pragma unroll
            for (int r = 0; r < 4; ++r) {
                u16 gam = f2b(__expf(-fmaxf(g4[r] + tbv[r], 0.f)));
                gbuf[(size_t)(b0 + quad * 4 + r) * HID + jt * 16 + cl] = gam;
            }
        }
    }
    __syncthreads();

    // ---- epilogue: x_c, imputations, X tail (fp8), loss partials ----
    float lossN = 0.f, lossD = 0.f;
    for (int i = tid; i < 16 * 35; i += 256) {
        int b = i / 35, f = i - b * 35;
        float xh = xhp[0][b][f] + xhp[1][b][f] + xhp[2][b][f] + xhp[3][b][f] + reg_b[f];
        float xv = x_sh[i], mv = m_sh[i];
        float xc = mv * xv + (1.f - mv) * xh;
        imput[((size_t)(b0 + b) * TLEN + t) * FEAT + f] = xc;
        u8* Xr = X + (size_t)(b0 + b) * KTOT;
        Xr[HID + f] = f2e4m3(xc);
        Xr[HID + FEAT + f] = f2e4m3(mv);
        lossN += fabsf(xv - xh) * mv;
        lossD += mv;
    }
    for (int i = tid; i < 16 * 58; i += 256) {
        int b = i / 58, k = i - b * 58;
        X[(size_t)(b0 + b) * KTOT + HID + 2 * FEAT + k] = 0;
    }
    #pragma unroll
    for (int off = 32; off; off >>= 1) {
        lossN += __shfl_down(lossN, off);
        lossD += __shfl_down(lossD, off);
    }
    if (lane == 0) { redbuf[wave] = lossN; redbuf[4 + wave] = lossD; }
    __syncthreads();
    if (tid == 0) {
        xnum_part[t * 256 + blockIdx.x] = redbuf[0] + redbuf[1] + redbuf[2] + redbuf[3];
        xden_part[t * 256 + blockIdx.x] = redbuf[4] + redbuf[5] + redbuf[6] + redbuf[7];
    }
}

// ---------------- stepB: MX-fp8 MFMA gates GEMM + fused LSTM cell ----------------
// 256M x 128N tile, 8 waves each 32M x 128N -> acc[2][8] = 64 f32/thread.
// R0/R1 lesson: acc[4][8]=128 f32 under the observed 128 arch-VGPR cap spilled
// ~70 regs/iter (453MB fetch of scratch). This shape fits even the worst model
// (64 acc + 16 av + 16 bv + ~30 addr <= 128 arch).
// Double-buffered LDS 96KB (As 2x32K, Bs 2x16K), 1 block/CU, grid 512 (2 rounds).
// Per kt: 4 phases {ds_read subtile -> prefetch STG -> barrier -> lgkmcnt(0) ->
// setprio(1) 4 MFMA setprio(0) -> barrier}; all 6 prefetches in phases 0-1 so the
// kt-boundary vmcnt(0) (after phase-3 MFMAs) is ~2 phases after last issue.
#define LDB2(p) { \
        v4i lo0 = *(const v4i*)(br + (2*(p)) * (16*128) + swlo); \
        v4i hi0 = *(const v4i*)(br + (2*(p)) * (16*128) + swhi); \
        bv[0] = (v8i){lo0[0], lo0[1], lo0[2], lo0[3], hi0[0], hi0[1], hi0[2], hi0[3]}; \
        v4i lo1 = *(const v4i*)(br + (2*(p)+1) * (16*128) + swlo); \
        v4i hi1 = *(const v4i*)(br + (2*(p)+1) * (16*128) + swhi); \
        bv[1] = (v8i){lo1[0], lo1[1], lo1[2], lo1[3], hi1[0], hi1[1], hi1[2], hi1[3]}; \
    }

#define STG(gptr, lds, it) \
    __builtin_amdgcn_global_load_lds((const __attribute__((address_space(1))) void*)((gptr) + (size_t)(it) * 8 * KTOT + kb), \
                                     (__attribute__((address_space(3))) void*)((lds) + (it) * 1024), 16, 0, 0)

#define MFMA4(p) \
    __builtin_amdgcn_s_setprio(1); \
    _Pragma("unroll") \
    for (int mi = 0; mi < 2; ++mi) { \
        acc[mi][2*(p)]   = __builtin_amdgcn_mfma_scale_f32_16x16x128_f8f6f4(av[mi], bv[0], acc[mi][2*(p)],   0, 0, 0, SCALE1, 0, SCALE1); \
        acc[mi][2*(p)+1] = __builtin_amdgcn_mfma_scale_f32_16x16x128_f8f6f4(av[mi], bv[1], acc[mi][2*(p)+1], 0, 0, 0, SCALE1, 0, SCALE1); \
    } \
    __builtin_amdgcn_s_setprio(0);

#define WAIT_LGKM asm volatile("s_waitcnt lgkmcnt(0)" ::: "memory"); __builtin_amdgcn_sched_barrier(0)
#define WAIT_VM   asm volatile("s_waitcnt vmcnt(0)" ::: "memory");   __builtin_amdgcn_sched_barrier(0)

__global__ __launch_bounds__(512, 2)
void stepB(const u8* __restrict__ X, const u8* __restrict__ W,
           const float* __restrict__ bias_r, const u16* __restrict__ gbuf,
           u16* __restrict__ c, u8* __restrict__ Xn,
           u16* __restrict__ h, int last) {
    __shared__ u8 As[2][256 * 128];   // 64 KB
    __shared__ u8 Bs[2][128 * 128];   // 32 KB
    int bid = blockIdx.x;
    int xcd = bid & 7, r0 = bid >> 3;            // r0 in [0,64)
    int mb = (xcd >> 1) * 4 + (r0 & 3);          // [0,16)   4 mb x 16 nb per XCD
    int nb = (xcd & 1) * 16 + (r0 >> 2);         // [0,32)
    int tid = threadIdx.x;
    int wave = tid >> 6, lane = tid & 63;
    int lrow = lane >> 3;            // 0..7 row within 8-row staging group
    int gchunk = (lane & 7) ^ lrow;  // swizzled global 16B-chunk to fetch
    int cl = lane & 15, quad = lane >> 4;
    int c7 = cl & 7;
    int swlo = ((2 * quad) ^ c7) << 4;
    int swhi = ((2 * quad + 1) ^ c7) << 4;

    // staging: wave stages A rows [wave*32,+32) (it=0..3), B rows [wave*16,+16) (it=0..1)
    const u8* gA = X + (size_t)(mb * 256 + wave * 32 + lrow) * KTOT + gchunk * 16;
    const u8* gB = W + (size_t)(nb * 128 + wave * 16 + lrow) * KTOT + gchunk * 16;
    u8* lA = (u8*)As + wave * (32 * 128);
    u8* lB = (u8*)Bs + wave * (16 * 128);

    f32x4 acc[2][8];
    #pragma unroll
    for (int mi = 0; mi < 2; ++mi)
        #pragma unroll
        for (int ni = 0; ni < 8; ++ni) acc[mi][ni] = (f32x4){0.f, 0.f, 0.f, 0.f};

    // prologue: stage K-step 0 into buffer 0
    {
        int kb = 0;
        #pragma unroll
        for (int it = 0; it < 4; ++it) STG(gA, lA, it);
        #pragma unroll
        for (int it = 0; it < 2; ++it) STG(gB, lB, it);
    }
    WAIT_VM;
    __builtin_amdgcn_s_barrier();

    for (int kt = 0; kt < 9; ++kt) {
        int cur = kt & 1, nxt = cur ^ 1;
        int kb = (kt + 1) * 128;
        const u8* ar = (u8*)As + cur * (256 * 128) + (wave * 32 + cl) * 128;
        const u8* br = (u8*)Bs + cur * (128 * 128) + cl * 128;
        u8* sA = lA + nxt * (256 * 128);
        u8* sB = lB + nxt * (128 * 128);
        bool st = (kt != 8);

        v8i av[2], bv[2];
        // ---- phase 0: av[0..1] + bv[0..1]; prefetch A it0,it1 + B it0 ----
        #pragma unroll
        for (int mi = 0; mi < 2; ++mi) {
            v4i lo = *(const v4i*)(ar + mi * (16 * 128) + swlo);
            v4i hi = *(const v4i*)(ar + mi * (16 * 128) + swhi);
            av[mi] = (v8i){lo[0], lo[1], lo[2], lo[3], hi[0], hi[1], hi[2], hi[3]};
        }
        LDB2(0);
        if (st) { STG(gA, sA, 0); STG(gA, sA, 1); STG(gB, sB, 0); }
        __builtin_amdgcn_s_barrier();
        WAIT_LGKM;
        MFMA4(0);
        __builtin_amdgcn_s_barrier();

        // ---- phase 1: bv[2..3]; prefetch A it2,it3 + B it1 ----
        LDB2(1);
        if (st) { STG(gA, sA, 2); STG(gA, sA, 3); STG(gB, sB, 1); }
        __builtin_amdgcn_s_barrier();
        WAIT_LGKM;
        MFMA4(1);
        __builtin_amdgcn_s_barrier();

        // ---- phase 2: bv[4..5] ----
        LDB2(2);
        __builtin_amdgcn_s_barrier();
        WAIT_LGKM;
        MFMA4(2);
        __builtin_amdgcn_s_barrier();

        // ---- phase 3: bv[6..7]; kt-boundary vmcnt AFTER MFMAs ----
        LDB2(3);
        __builtin_amdgcn_s_barrier();
        WAIT_LGKM;
        MFMA4(3);
        WAIT_VM;
        __builtin_amdgcn_s_barrier();
    }

    // fused LSTM epilogue; for t<47 write X_hdec(t+1) = h*gamma(t+1) in fp8, for t=47 write h bf16.
    #pragma unroll
    for (int mi = 0; mi < 2; ++mi) {
        #pragma unroll
        for (int r = 0; r < 4; ++r) {
            int b = mb * 256 + wave * 32 + mi * 16 + quad * 4 + r;
            #pragma unroll
            for (int jh = 0; jh < 2; ++jh) {
                int jl = jh * 16 + cl;
                int j = nb * 32 + jl;
                float iv = acc[mi][jh + 0][r] + bias_r[nb * 128 + jl];
                float fv = acc[mi][jh + 2][r] + bias_r[nb * 128 + 32 + jl];
                float gg = acc[mi][jh + 4][r] + bias_r[nb * 128 + 64 + jl];
                float ov = acc[mi][jh + 6][r] + bias_r[nb * 128 + 96 + jl];
                iv = sigf(iv); fv = sigf(fv); ov = sigf(ov); gg = tanh_fast(gg);
                size_t idx = (size_t)b * HID + j;
                float cn = fv * b2f(c[idx]) + iv * gg;
                c[idx] = f2b(cn);
                float hn = ov * tanh_fast(cn);
                if (last) {
                    h[idx] = f2b(hn);
                } else {
                    Xn[(size_t)b * KTOT + j] = f2e4m3(hn * b2f(gbuf[idx]));
                }
            }
        }
    }
}

// ---------------- final kernels (atomic-free) ----------------
__global__ __launch_bounds__(256) void finalY(const u16* __restrict__ h, const float* __restrict__ out_W,
                                              const float* __restrict__ out_b, const float* __restrict__ labels,
                                              const float* __restrict__ is_train, float* __restrict__ preds,
                                              float* __restrict__ bce_part, float* __restrict__ it_part) {
    __shared__ float wbuf[8];
    int tid = threadIdx.x;
    int wave = tid >> 6, lane = tid & 63;
    int cl = lane & 15, quad = lane >> 4;
    int b = blockIdx.x * 16 + wave * 4 + quad;
    const u16x8* hp = (const u16x8*)(h + (size_t)b * HID + cl * 64);
    const float4* wp = (const float4*)(out_W + cl * 64);
    float s = 0.f;
    #pragma unroll
    for (int i = 0; i < 8; ++i) {
        u16x8 hv = hp[i];
        float4 wa = wp[2 * i], wb = wp[2 * i + 1];
        s += b2f(hv[0]) * wa.x + b2f(hv[1]) * wa.y + b2f(hv[2]) * wa.z + b2f(hv[3]) * wa.w
           + b2f(hv[4]) * wb.x + b2f(hv[5]) * wb.y + b2f(hv[6]) * wb.z + b2f(hv[7]) * wb.w;
    }
    s += __shfl_down(s, 8, 16);
    s += __shfl_down(s, 4, 16);
    s += __shfl_down(s, 2, 16);
    s += __shfl_down(s, 1, 16);
    float v1 = 0.f, v2 = 0.f;
    if (cl == 0) {
        float y = s + out_b[0];
        preds[b] = 1.f / (1.f + expf(-y));
        float lab = labels[b], it = is_train[b];
        float mv = fmaxf(-y, 0.f);
        float bce = y - y * lab + mv + logf(expf(-mv) + expf(-y - mv));
        v1 = bce * it; v2 = it;
    }
    v1 += __shfl_xor(v1, 16); v2 += __shfl_xor(v2, 16);
    v1 += __shfl_xor(v1, 32); v2 += __shfl_xor(v2, 32);
    if (lane == 0) { wbuf[wave] = v1; wbuf[4 + wave] = v2; }
    __syncthreads();
    if (tid == 0) {
        bce_part[blockIdx.x] = wbuf[0] + wbuf[1] + wbuf[2] + wbuf[3];
        it_part[blockIdx.x]  = wbuf[4] + wbuf[5] + wbuf[6] + wbuf[7];
    }
}

__global__ __launch_bounds__(256) void finalZ(const float* __restrict__ xnum, const float* __restrict__ xden,
                                              const float* __restrict__ bce_part, const float* __restrict__ it_part,
                                              float* __restrict__ out0) {
    __shared__ float wbuf[12];
    int tid = threadIdx.x, wave = tid >> 6, lane = tid & 63;
    float bs = bce_part[tid], is = it_part[tid];
    #pragma unroll
    for (int off = 32; off; off >>= 1) { bs += __shfl_down(bs, off); is += __shfl_down(is, off); }
    float xl = 0.f;
    for (int t = wave; t < TLEN; t += 4) {
        float n = 0.f, d = 0.f;
        #pragma unroll
        for (int i = 0; i < 4; ++i) { n += xnum[t * 256 + lane + i * 64]; d += xden[t * 256 + lane + i * 64]; }
        #pragma unroll
        for (int off = 32; off; off >>= 1) { n += __shfl_down(n, off); d += __shfl_down(d, off); }
        if (lane == 0) xl += n / (d + 1e-5f);
    }
    if (lane == 0) { wbuf[wave] = xl; wbuf[4 + wave] = bs; wbuf[8 + wave] = is; }
    __syncthreads();
    if (tid == 0) {
        float XL = wbuf[0] + wbuf[1] + wbuf[2] + wbuf[3];
        float BS = wbuf[4] + wbuf[5] + wbuf[6] + wbuf[7];
        float IS = wbuf[8] + wbuf[9] + wbuf[10] + wbuf[11];
        out0[0] = 0.3f * XL + BS / (IS + 1e-5f);
    }
}

// ---------------- launch ----------------
extern "C" void kernel_launch(void* const* d_in, const int* in_sizes, int n_in,
                              void* d_out, int out_size, void* d_ws, size_t ws_size,
                              hipStream_t stream) {
    const float* values   = (const float*)d_in[0];
    const float* masks    = (const float*)d_in[1];
    const float* deltas   = (const float*)d_in[2];
    const float* labels   = (const float*)d_in[3];
    const float* is_train = (const float*)d_in[4];
    const float* td_W     = (const float*)d_in[5];
    const float* td_b     = (const float*)d_in[6];
    const float* W_ih     = (const float*)d_in[7];
    const float* W_hh     = (const float*)d_in[8];
    const float* b_ih     = (const float*)d_in[9];
    const float* b_hh     = (const float*)d_in[10];
    const float* reg_W    = (const float*)d_in[11];
    const float* reg_b    = (const float*)d_in[12];
    const float* out_W    = (const float*)d_in[13];
    const float* out_b    = (const float*)d_in[14];

    float* out = (float*)d_out;

    // workspace (bytes): c bf16[BH] | h bf16[BH] | gbuf bf16[BH] | Xa u8[B*KTOT] | Xb u8[B*KTOT]
    //                    | W8 u8[H4*KTOT] | bias f32[H4] | tdWtb bf16[64K] | regW8 u8[48*1024] | parts
    u16*   c      = (u16*)d_ws;
    u16*   h      = c + BH;
    u16*   gbuf   = h + BH;
    u8*    Xa     = (u8*)(gbuf + BH);
    u8*    Xb     = Xa + (size_t)BDIM * KTOT;
    u8*    W8     = Xb + (size_t)BDIM * KTOT;
    float* bias_r = (float*)(W8 + (size_t)H4 * KTOT);
    u16*   tdWtb  = (u16*)(bias_r + H4);
    u8*    regW8  = (u8*)(tdWtb + 1024 * 64);
    float* xnum_part = (float*)(regW8 + 48 * 1024);
    float* xden_part = xnum_part + TLEN * 256;
    float* bce_part  = xden_part + TLEN * 256;
    float* it_part   = bce_part + 256;

    hipMemsetAsync(c, 0, BH * sizeof(u16), stream);                 // c = 0
    hipMemsetAsync(Xa, 0, (size_t)BDIM * KTOT, stream);             // X_hdec(0) = 0

    prep_w<<<H4, 256, 0, stream>>>(W_hh, W_ih, W8);
    prep_bias<<<H4 / 256, 256, 0, stream>>>(b_ih, b_hh, bias_r);
    prep_tdwtb<<<256, 256, 0, stream>>>(td_W, tdWtb);
    prep_regw8<<<48, 256, 0, stream>>>(reg_W, regW8);

    float* imput = out + 1 + BDIM;
    for (int t = 0; t < TLEN; t++) {
        u8* cur = (t & 1) ? Xb : Xa;
        u8* nxt = (t & 1) ? Xa : Xb;
        stepR<<<BDIM / 16, 256, 0, stream>>>(values, masks, deltas, tdWtb, td_b, regW8, reg_b,
                                             cur, gbuf, imput, xnum_part, xden_part, t, t < TLEN - 1);
        stepB<<<512, 512, 0, stream>>>(cur, W8, bias_r, gbuf, c, nxt, h, t == TLEN - 1);
    }
    finalY<<<BDIM / 16, 256, 0, stream>>>(h, out_W, out_b, labels, is_train, out + 1, bce_part, it_part);
    finalZ<<<1, 256, 0, stream>>>(xnum_part, xden_part, bce_part, it_part, out);
}

// Round 4
// 8576.509 us; speedup vs baseline: 1.6921x; 1.5844x over previous
//
#include <hip/hip_runtime.h>
#include <math.h>

// Problem constants
#define BDIM 4096
#define TLEN 48
#define FEAT 35
#define HID 1024
#define H4 4096
#define KTOT 1152      // 1024 (hh) + 128 (ih, 70 real + 58 zero pad)

#define BH ((size_t)BDIM * HID)

typedef unsigned short u16;
typedef unsigned char u8;
typedef __bf16 bf16x8 __attribute__((ext_vector_type(8)));
typedef float f32x4 __attribute__((ext_vector_type(4)));
typedef u16 u16x8 __attribute__((ext_vector_type(8)));
typedef int v8i __attribute__((ext_vector_type(8)));
typedef int v4i __attribute__((ext_vector_type(4)));

#define SCALE1 0x7F7F7F7F   // E8M0 scale = 1.0 in every byte

__device__ __forceinline__ float b2f(u16 u) {
    union { float f; unsigned i; } v; v.i = ((unsigned)u) << 16; return v.f;
}
__device__ __forceinline__ u16 f2b(float f) {
    union { float f; unsigned i; } v; v.f = f;
    unsigned r = v.i + 0x7FFF + ((v.i >> 16) & 1);
    return (u16)(r >> 16);
}
__device__ __forceinline__ unsigned pk4_fp8(float a, float b, float c, float d) {
    int lo = __builtin_amdgcn_cvt_pk_fp8_f32(a, b, 0, false);
    int hi = __builtin_amdgcn_cvt_pk_fp8_f32(c, d, lo, true);
    return (unsigned)hi;
}
__device__ __forceinline__ u8 f2e4m3(float f) {
    return (u8)(__builtin_amdgcn_cvt_pk_fp8_f32(f, 0.f, 0, false) & 0xFF);
}
__device__ __forceinline__ float sigf(float x) { return __builtin_amdgcn_rcpf(1.f + __expf(-x)); }
__device__ __forceinline__ float tanh_fast(float x) { return 1.f - 2.f * __builtin_amdgcn_rcpf(1.f + __expf(2.f * x)); }

// ---------------- prep kernels ----------------
// Combined fp8 weight matrix W[4096][1152], rows reordered:
// orig n = g*HID + j  ->  new n = (j>>5)*128 + g*32 + (j&31)
__global__ __launch_bounds__(256) void prep_w(const float* __restrict__ W_hh, const float* __restrict__ W_ih,
                                              u8* __restrict__ W) {
    int newn = blockIdx.x;
    int nbk = newn >> 7, rem = newn & 127, g = rem >> 5, jl = rem & 31;
    int orig = g * HID + nbk * 32 + jl;
    u8* dst = W + (size_t)newn * KTOT;
    const float* src = W_hh + (size_t)orig * HID;
    const float* src2 = W_ih + (size_t)orig * (2 * FEAT);
    for (int k4 = threadIdx.x; k4 < KTOT / 4; k4 += 256) {
        int k = k4 * 4;
        float f0, f1, f2, f3;
        if (k < HID) {
            f0 = src[k]; f1 = src[k + 1]; f2 = src[k + 2]; f3 = src[k + 3];
        } else {
            int q = k - HID;
            f0 = (q     < 2 * FEAT) ? src2[q]     : 0.f;
            f1 = (q + 1 < 2 * FEAT) ? src2[q + 1] : 0.f;
            f2 = (q + 2 < 2 * FEAT) ? src2[q + 2] : 0.f;
            f3 = (q + 3 < 2 * FEAT) ? src2[q + 3] : 0.f;
        }
        *(unsigned*)(dst + k) = pk4_fp8(f0, f1, f2, f3);
    }
}

__global__ __launch_bounds__(256) void prep_bias(const float* __restrict__ b_ih, const float* __restrict__ b_hh,
                                                 float* __restrict__ bias_r) {
    int newn = blockIdx.x * 256 + threadIdx.x;
    int nbk = newn >> 7, rem = newn & 127, g = rem >> 5, jl = rem & 31;
    int orig = g * HID + nbk * 32 + jl;
    bias_r[newn] = b_ih[orig] + b_hh[orig];
}

// tdWtb[j][f] bf16, [1024][64], f>=35 zero.
__global__ __launch_bounds__(256) void prep_tdwtb(const float* __restrict__ td_W, u16* __restrict__ tdWtb) {
    int idx = blockIdx.x * 256 + threadIdx.x;
    int row = idx >> 6, f = idx & 63;
    tdWtb[idx] = (f < FEAT) ? f2b(td_W[(size_t)row * FEAT + f]) : (u16)0;
}

// regW8[f][k] fp8, [48][1024], f>=35 zero.
__global__ __launch_bounds__(256) void prep_regw8(const float* __restrict__ reg_W, u8* __restrict__ regW8) {
    int row = blockIdx.x;           // 48
    int k = threadIdx.x * 4;        // 1024
    float f0 = 0.f, f1 = 0.f, f2 = 0.f, f3 = 0.f;
    if (row < FEAT) {
        const float* s = reg_W + (size_t)row * HID + k;
        f0 = s[0]; f1 = s[1]; f2 = s[2]; f3 = s[3];
    }
    *(unsigned*)(regW8 + (size_t)row * 1024 + k) = pk4_fp8(f0, f1, f2, f3);
}

// ---------------- stepR: regression + x_c + loss + gamma(t+1) ----------------
__global__ __launch_bounds__(256) void stepR(const float* __restrict__ values, const float* __restrict__ masks,
                                             const float* __restrict__ deltas, const u16* __restrict__ tdWtb,
                                             const float* __restrict__ td_b, const u8* __restrict__ regW8,
                                             const float* __restrict__ reg_b, u8* __restrict__ X,
                                             u16* __restrict__ gbuf, float* __restrict__ imput,
                                             float* __restrict__ xnum_part, float* __restrict__ xden_part,
                                             int t, int gflag) {
    __shared__ u16 d_sh[16 * 64];          // bf16 d(t+1), 16B-chunk XOR swizzled per row
    __shared__ float x_sh[16 * 35], m_sh[16 * 35];
    __shared__ float xhp[4][16][49];       // per-wave regression partials (padded)
    __shared__ float redbuf[8];

    int tid = threadIdx.x;
    int wave = tid >> 6, lane = tid & 63;
    int cl = lane & 15, quad = lane >> 4;
    int b0 = blockIdx.x * 16;

    for (int i = tid; i < 16 * 35; i += 256) {
        int b = i / 35, f = i - b * 35;
        size_t g = ((size_t)(b0 + b) * TLEN + t) * FEAT + f;
        x_sh[i] = values[g];
        m_sh[i] = masks[g];
    }
    if (gflag && tid < 128) {
        int b = tid >> 3, cch = tid & 7;
        const float* drow = deltas + ((size_t)(b0 + b) * TLEN + (t + 1)) * FEAT;
        u16x8 tv;
        #pragma unroll
        for (int k = 0; k < 8; ++k) {
            int f = cch * 8 + k;
            tv[k] = (f < FEAT) ? f2b(drow[f]) : (u16)0;
        }
        int csw = cch ^ (b & 7);
        *(u16x8*)(d_sh + b * 64 + csw * 8) = tv;
    }
    __syncthreads();

    // ---- regression via MX-fp8 MFMA (K split: wave covers K [wave*256, +256)) ----
    f32x4 racc[3];
    #pragma unroll
    for (int nt = 0; nt < 3; ++nt) racc[nt] = (f32x4){0.f, 0.f, 0.f, 0.f};
    const u8* xrow = X + (size_t)(b0 + cl) * KTOT + wave * 256;
    #pragma unroll
    for (int it = 0; it < 2; ++it) {
        v8i av = *(const v8i*)(xrow + it * 128 + quad * 32);
        #pragma unroll
        for (int nt = 0; nt < 3; ++nt) {
            v8i bvv = *(const v8i*)(regW8 + (size_t)(nt * 16 + cl) * 1024 + wave * 256 + it * 128 + quad * 32);
            racc[nt] = __builtin_amdgcn_mfma_scale_f32_16x16x128_f8f6f4(
                av, bvv, racc[nt], 0, 0, 0, SCALE1, 0, SCALE1);
        }
    }
    #pragma unroll
    for (int nt = 0; nt < 3; ++nt)
        #pragma unroll
        for (int r = 0; r < 4; ++r)
            xhp[wave][quad * 4 + r][nt * 16 + cl] = racc[nt][r];

    // ---- gamma MFMA (bf16): wave covers j-tiles [wave*16, wave*16+16) ----
    if (gflag) {
        int swc0 = quad ^ (cl & 7);
        int swc1 = (4 + quad) ^ (cl & 7);
        bf16x8 a0 = *(const bf16x8*)(d_sh + cl * 64 + swc0 * 8);
        bf16x8 a1 = *(const bf16x8*)(d_sh + cl * 64 + swc1 * 8);
        #pragma unroll 4
        for (int jt2 = 0; jt2 < 16; ++jt2) {
            int jt = wave * 16 + jt2;
            const u16* tw = tdWtb + (size_t)(jt * 16 + cl) * 64;
            bf16x8 b0v = *(const bf16x8*)(tw + quad * 8);
            bf16x8 b1v = *(const bf16x8*)(tw + 32 + quad * 8);
            f32x4 g4 = (f32x4){0.f, 0.f, 0.f, 0.f};
            g4 = __builtin_amdgcn_mfma_f32_16x16x32_bf16(a0, b0v, g4, 0, 0, 0);
            g4 = __builtin_amdgcn_mfma_f32_16x16x32_bf16(a1, b1v, g4, 0, 0, 0);
            float4 tb = *(const float4*)(td_b + jt * 16 + quad * 4);
            float tbv[4] = {tb.x, tb.y, tb.z, tb.w};
            #pragma unroll
            for (int r = 0; r < 4; ++r) {
                u16 gam = f2b(__expf(-fmaxf(g4[r] + tbv[r], 0.f)));
                gbuf[(size_t)(b0 + quad * 4 + r) * HID + jt * 16 + cl] = gam;
            }
        }
    }
    __syncthreads();

    // ---- epilogue: x_c, imputations, X tail (fp8), loss partials ----
    float lossN = 0.f, lossD = 0.f;
    for (int i = tid; i < 16 * 35; i += 256) {
        int b = i / 35, f = i - b * 35;
        float xh = xhp[0][b][f] + xhp[1][b][f] + xhp[2][b][f] + xhp[3][b][f] + reg_b[f];
        float xv = x_sh[i], mv = m_sh[i];
        float xc = mv * xv + (1.f - mv) * xh;
        imput[((size_t)(b0 + b) * TLEN + t) * FEAT + f] = xc;
        u8* Xr = X + (size_t)(b0 + b) * KTOT;
        Xr[HID + f] = f2e4m3(xc);
        Xr[HID + FEAT + f] = f2e4m3(mv);
        lossN += fabsf(xv - xh) * mv;
        lossD += mv;
    }
    for (int i = tid; i < 16 * 58; i += 256) {
        int b = i / 58, k = i - b * 58;
        X[(size_t)(b0 + b) * KTOT + HID + 2 * FEAT + k] = 0;
    }
    #pragma unroll
    for (int off = 32; off; off >>= 1) {
        lossN += __shfl_down(lossN, off);
        lossD += __shfl_down(lossD, off);
    }
    if (lane == 0) { redbuf[wave] = lossN; redbuf[4 + wave] = lossD; }
    __syncthreads();
    if (tid == 0) {
        xnum_part[t * 256 + blockIdx.x] = redbuf[0] + redbuf[1] + redbuf[2] + redbuf[3];
        xden_part[t * 256 + blockIdx.x] = redbuf[4] + redbuf[5] + redbuf[6] + redbuf[7];
    }
}

// ---------------- stepB: MX-fp8 MFMA gates GEMM + fused LSTM cell ----------------
// PROVEN geometry (the 2669us baseline): 256 threads / 4 waves, block tile 256M x 128N,
// wave tile 64M x 128N, acc[4][8] in AGPRs, VGPR 112, no spill. R1-R3 lesson: 512-thread
// 8-wave blocks get a 128 arch-VGPR cap and spill catastrophically -- do not use them.
// This round changes ONLY the schedule: double-buffered LDS (As 2x32K + Bs 2x16K = 96KB,
// 1 block/CU) with the minimum 2-phase pipeline: issue next-tile global_load_lds FIRST,
// then ds_read+MFMA current buffer (compiler schedules lgkmcnt), then ONE vmcnt(0)+barrier
// per K-step. The staging latency now lands after ~500cy of compute instead of before it.
#define STG(gptr, lds, it) \
    __builtin_amdgcn_global_load_lds((const __attribute__((address_space(1))) void*)((gptr) + (size_t)(it) * 8 * KTOT + kb), \
                                     (__attribute__((address_space(3))) void*)((lds) + (it) * 1024), 16, 0, 0)

#define WAIT_VM   asm volatile("s_waitcnt vmcnt(0)" ::: "memory");   __builtin_amdgcn_sched_barrier(0)

__global__ __launch_bounds__(256, 2)
void stepB(const u8* __restrict__ X, const u8* __restrict__ W,
           const float* __restrict__ bias_r, const u16* __restrict__ gbuf,
           u16* __restrict__ c, u8* __restrict__ Xn,
           u16* __restrict__ h, int last) {
    __shared__ u8 As[2][256 * 128];   // 64 KB
    __shared__ u8 Bs[2][128 * 128];   // 32 KB
    int bid = blockIdx.x;
    int xcd = bid & 7, r0 = bid >> 3;            // r0 in [0,64)
    int mb = (xcd >> 1) * 4 + (r0 & 3);          // [0,16)   4 mb x 16 nb per XCD (~3.4MB L2 set)
    int nb = (xcd & 1) * 16 + (r0 >> 2);         // [0,32)
    int tid = threadIdx.x;
    int wave = tid >> 6, lane = tid & 63;
    int lrow = lane >> 3;            // 0..7 row within 8-row staging group
    int gchunk = (lane & 7) ^ lrow;  // swizzled global 16B-chunk to fetch
    int cl = lane & 15, quad = lane >> 4;
    int c7 = cl & 7;
    int swlo = ((2 * quad) ^ c7) << 4;
    int swhi = ((2 * quad + 1) ^ c7) << 4;

    // staging: wave stages A rows [wave*64,+64) (it=0..7), B rows [wave*32,+32) (it=0..3)
    const u8* gA = X + (size_t)(mb * 256 + wave * 64 + lrow) * KTOT + gchunk * 16;
    const u8* gB = W + (size_t)(nb * 128 + wave * 32 + lrow) * KTOT + gchunk * 16;

    f32x4 acc[4][8];
    #pragma unroll
    for (int mi = 0; mi < 4; ++mi)
        #pragma unroll
        for (int ni = 0; ni < 8; ++ni) acc[mi][ni] = (f32x4){0.f, 0.f, 0.f, 0.f};

    // prologue: stage K-step 0 into buffer 0
    {
        int kb = 0;
        u8* sA = (u8*)As + wave * (64 * 128);
        u8* sB = (u8*)Bs + wave * (32 * 128);
        #pragma unroll
        for (int it = 0; it < 8; ++it) STG(gA, sA, it);
        #pragma unroll
        for (int it = 0; it < 4; ++it) STG(gB, sB, it);
    }
    WAIT_VM;
    __builtin_amdgcn_s_barrier();

    for (int kt = 0; kt < 9; ++kt) {
        int cur = kt & 1, nxt = cur ^ 1;
        // ---- issue prefetch of K-step kt+1 into the other buffer (before compute) ----
        if (kt != 8) {
            int kb = (kt + 1) * 128;
            u8* sA = (u8*)As + nxt * (256 * 128) + wave * (64 * 128);
            u8* sB = (u8*)Bs + nxt * (128 * 128) + wave * (32 * 128);
            #pragma unroll
            for (int it = 0; it < 8; ++it) STG(gA, sA, it);
            #pragma unroll
            for (int it = 0; it < 4; ++it) STG(gB, sB, it);
        }
        __builtin_amdgcn_sched_barrier(0);   // keep prefetch issue ahead of compute

        // ---- compute on current buffer (compiler interleaves ds_read/MFMA) ----
        const u8* arb = (u8*)As + cur * (256 * 128) + (wave * 64 + cl) * 128;
        const u8* brb = (u8*)Bs + cur * (128 * 128) + cl * 128;
        v8i av[4];
        #pragma unroll
        for (int mi = 0; mi < 4; ++mi) {
            v4i lo = *(const v4i*)(arb + mi * (16 * 128) + swlo);
            v4i hi = *(const v4i*)(arb + mi * (16 * 128) + swhi);
            av[mi] = (v8i){lo[0], lo[1], lo[2], lo[3], hi[0], hi[1], hi[2], hi[3]};
        }
        #pragma unroll
        for (int ni = 0; ni < 8; ++ni) {
            v4i lo = *(const v4i*)(brb + ni * (16 * 128) + swlo);
            v4i hi = *(const v4i*)(brb + ni * (16 * 128) + swhi);
            v8i bvv = (v8i){lo[0], lo[1], lo[2], lo[3], hi[0], hi[1], hi[2], hi[3]};
            #pragma unroll
            for (int mi = 0; mi < 4; ++mi)
                acc[mi][ni] = __builtin_amdgcn_mfma_scale_f32_16x16x128_f8f6f4(
                    av[mi], bvv, acc[mi][ni], 0, 0, 0, SCALE1, 0, SCALE1);
        }

        // ---- K-step boundary: prefetch (issued ~500cy ago) must be in LDS ----
        WAIT_VM;
        __builtin_amdgcn_s_barrier();
    }

    // fused LSTM epilogue; for t<47 write X_hdec(t+1) = h*gamma(t+1) in fp8, for t=47 write h bf16.
    #pragma unroll
    for (int mi = 0; mi < 4; ++mi) {
        #pragma unroll
        for (int r = 0; r < 4; ++r) {
            int b = mb * 256 + wave * 64 + mi * 16 + quad * 4 + r;
            #pragma unroll
            for (int jh = 0; jh < 2; ++jh) {
                int jl = jh * 16 + cl;
                int j = nb * 32 + jl;
                float iv = acc[mi][jh + 0][r] + bias_r[nb * 128 + jl];
                float fv = acc[mi][jh + 2][r] + bias_r[nb * 128 + 32 + jl];
                float gg = acc[mi][jh + 4][r] + bias_r[nb * 128 + 64 + jl];
                float ov = acc[mi][jh + 6][r] + bias_r[nb * 128 + 96 + jl];
                iv = sigf(iv); fv = sigf(fv); ov = sigf(ov); gg = tanh_fast(gg);
                size_t idx = (size_t)b * HID + j;
                float cn = fv * b2f(c[idx]) + iv * gg;
                c[idx] = f2b(cn);
                float hn = ov * tanh_fast(cn);
                if (last) {
                    h[idx] = f2b(hn);
                } else {
                    Xn[(size_t)b * KTOT + j] = f2e4m3(hn * b2f(gbuf[idx]));
                }
            }
        }
    }
}

// ---------------- final kernels (atomic-free) ----------------
__global__ __launch_bounds__(256) void finalY(const u16* __restrict__ h, const float* __restrict__ out_W,
                                              const float* __restrict__ out_b, const float* __restrict__ labels,
                                              const float* __restrict__ is_train, float* __restrict__ preds,
                                              float* __restrict__ bce_part, float* __restrict__ it_part) {
    __shared__ float wbuf[8];
    int tid = threadIdx.x;
    int wave = tid >> 6, lane = tid & 63;
    int cl = lane & 15, quad = lane >> 4;
    int b = blockIdx.x * 16 + wave * 4 + quad;
    const u16x8* hp = (const u16x8*)(h + (size_t)b * HID + cl * 64);
    const float4* wp = (const float4*)(out_W + cl * 64);
    float s = 0.f;
    #pragma unroll
    for (int i = 0; i < 8; ++i) {
        u16x8 hv = hp[i];
        float4 wa = wp[2 * i], wb = wp[2 * i + 1];
        s += b2f(hv[0]) * wa.x + b2f(hv[1]) * wa.y + b2f(hv[2]) * wa.z + b2f(hv[3]) * wa.w
           + b2f(hv[4]) * wb.x + b2f(hv[5]) * wb.y + b2f(hv[6]) * wb.z + b2f(hv[7]) * wb.w;
    }
    s += __shfl_down(s, 8, 16);
    s += __shfl_down(s, 4, 16);
    s += __shfl_down(s, 2, 16);
    s += __shfl_down(s, 1, 16);
    float v1 = 0.f, v2 = 0.f;
    if (cl == 0) {
        float y = s + out_b[0];
        preds[b] = 1.f / (1.f + expf(-y));
        float lab = labels[b], it = is_train[b];
        float mv = fmaxf(-y, 0.f);
        float bce = y - y * lab + mv + logf(expf(-mv) + expf(-y - mv));
        v1 = bce * it; v2 = it;
    }
    v1 += __shfl_xor(v1, 16); v2 += __shfl_xor(v2, 16);
    v1 += __shfl_xor(v1, 32); v2 += __shfl_xor(v2, 32);
    if (lane == 0) { wbuf[wave] = v1; wbuf[4 + wave] = v2; }
    __syncthreads();
    if (tid == 0) {
        bce_part[blockIdx.x] = wbuf[0] + wbuf[1] + wbuf[2] + wbuf[3];
        it_part[blockIdx.x]  = wbuf[4] + wbuf[5] + wbuf[6] + wbuf[7];
    }
}

__global__ __launch_bounds__(256) void finalZ(const float* __restrict__ xnum, const float* __restrict__ xden,
                                              const float* __restrict__ bce_part, const float* __restrict__ it_part,
                                              float* __restrict__ out0) {
    __shared__ float wbuf[12];
    int tid = threadIdx.x, wave = tid >> 6, lane = tid & 63;
    float bs = bce_part[tid], is = it_part[tid];
    #pragma unroll
    for (int off = 32; off; off >>= 1) { bs += __shfl_down(bs, off); is += __shfl_down(is, off); }
    float xl = 0.f;
    for (int t = wave; t < TLEN; t += 4) {
        float n = 0.f, d = 0.f;
        #pragma unroll
        for (int i = 0; i < 4; ++i) { n += xnum[t * 256 + lane + i * 64]; d += xden[t * 256 + lane + i * 64]; }
        #pragma unroll
        for (int off = 32; off; off >>= 1) { n += __shfl_down(n, off); d += __shfl_down(d, off); }
        if (lane == 0) xl += n / (d + 1e-5f);
    }
    if (lane == 0) { wbuf[wave] = xl; wbuf[4 + wave] = bs; wbuf[8 + wave] = is; }
    __syncthreads();
    if (tid == 0) {
        float XL = wbuf[0] + wbuf[1] + wbuf[2] + wbuf[3];
        float BS = wbuf[4] + wbuf[5] + wbuf[6] + wbuf[7];
        float IS = wbuf[8] + wbuf[9] + wbuf[10] + wbuf[11];
        out0[0] = 0.3f * XL + BS / (IS + 1e-5f);
    }
}

// ---------------- launch ----------------
extern "C" void kernel_launch(void* const* d_in, const int* in_sizes, int n_in,
                              void* d_out, int out_size, void* d_ws, size_t ws_size,
                              hipStream_t stream) {
    const float* values   = (const float*)d_in[0];
    const float* masks    = (const float*)d_in[1];
    const float* deltas   = (const float*)d_in[2];
    const float* labels   = (const float*)d_in[3];
    const float* is_train = (const float*)d_in[4];
    const float* td_W     = (const float*)d_in[5];
    const float* td_b     = (const float*)d_in[6];
    const float* W_ih     = (const float*)d_in[7];
    const float* W_hh     = (const float*)d_in[8];
    const float* b_ih     = (const float*)d_in[9];
    const float* b_hh     = (const float*)d_in[10];
    const float* reg_W    = (const float*)d_in[11];
    const float* reg_b    = (const float*)d_in[12];
    const float* out_W    = (const float*)d_in[13];
    const float* out_b    = (const float*)d_in[14];

    float* out = (float*)d_out;

    // workspace (bytes): c bf16[BH] | h bf16[BH] | gbuf bf16[BH] | Xa u8[B*KTOT] | Xb u8[B*KTOT]
    //                    | W8 u8[H4*KTOT] | bias f32[H4] | tdWtb bf16[64K] | regW8 u8[48*1024] | parts
    u16*   c      = (u16*)d_ws;
    u16*   h      = c + BH;
    u16*   gbuf   = h + BH;
    u8*    Xa     = (u8*)(gbuf + BH);
    u8*    Xb     = Xa + (size_t)BDIM * KTOT;
    u8*    W8     = Xb + (size_t)BDIM * KTOT;
    float* bias_r = (float*)(W8 + (size_t)H4 * KTOT);
    u16*   tdWtb  = (u16*)(bias_r + H4);
    u8*    regW8  = (u8*)(tdWtb + 1024 * 64);
    float* xnum_part = (float*)(regW8 + 48 * 1024);
    float* xden_part = xnum_part + TLEN * 256;
    float* bce_part  = xden_part + TLEN * 256;
    float* it_part   = bce_part + 256;

    hipMemsetAsync(c, 0, BH * sizeof(u16), stream);                 // c = 0
    hipMemsetAsync(Xa, 0, (size_t)BDIM * KTOT, stream);             // X_hdec(0) = 0

    prep_w<<<H4, 256, 0, stream>>>(W_hh, W_ih, W8);
    prep_bias<<<H4 / 256, 256, 0, stream>>>(b_ih, b_hh, bias_r);
    prep_tdwtb<<<256, 256, 0, stream>>>(td_W, tdWtb);
    prep_regw8<<<48, 256, 0, stream>>>(reg_W, regW8);

    float* imput = out + 1 + BDIM;
    for (int t = 0; t < TLEN; t++) {
        u8* cur = (t & 1) ? Xb : Xa;
        u8* nxt = (t & 1) ? Xa : Xb;
        stepR<<<BDIM / 16, 256, 0, stream>>>(values, masks, deltas, tdWtb, td_b, regW8, reg_b,
                                             cur, gbuf, imput, xnum_part, xden_part, t, t < TLEN - 1);
        stepB<<<512, 256, 0, stream>>>(cur, W8, bias_r, gbuf, c, nxt, h, t == TLEN - 1);
    }
    finalY<<<BDIM / 16, 256, 0, stream>>>(h, out_W, out_b, labels, is_train, out + 1, bce_part, it_part);
    finalZ<<<1, 256, 0, stream>>>(xnum_part, xden_part, bce_part, it_part, out);
}

// Round 6
// 2666.313 us; speedup vs baseline: 5.4427x; 3.2166x over previous
//
#include <hip/hip_runtime.h>
#include <math.h>

// Problem constants
#define BDIM 4096
#define TLEN 48
#define FEAT 35
#define HID 1024
#define H4 4096
#define KTOT 1152      // 1024 (hh) + 128 (ih, 70 real + 58 zero pad)

#define BH ((size_t)BDIM * HID)

typedef unsigned short u16;
typedef unsigned char u8;
typedef __bf16 bf16x8 __attribute__((ext_vector_type(8)));
typedef float f32x4 __attribute__((ext_vector_type(4)));
typedef u16 u16x8 __attribute__((ext_vector_type(8)));
typedef int v8i __attribute__((ext_vector_type(8)));
typedef int v4i __attribute__((ext_vector_type(4)));

#define SCALE1 0x7F7F7F7F   // E8M0 scale = 1.0 in every byte

__device__ __forceinline__ float b2f(u16 u) {
    union { float f; unsigned i; } v; v.i = ((unsigned)u) << 16; return v.f;
}
__device__ __forceinline__ u16 f2b(float f) {
    union { float f; unsigned i; } v; v.f = f;
    unsigned r = v.i + 0x7FFF + ((v.i >> 16) & 1);
    return (u16)(r >> 16);
}
__device__ __forceinline__ unsigned pk4_fp8(float a, float b, float c, float d) {
    int lo = __builtin_amdgcn_cvt_pk_fp8_f32(a, b, 0, false);
    int hi = __builtin_amdgcn_cvt_pk_fp8_f32(c, d, lo, true);
    return (unsigned)hi;
}
__device__ __forceinline__ u8 f2e4m3(float f) {
    return (u8)(__builtin_amdgcn_cvt_pk_fp8_f32(f, 0.f, 0, false) & 0xFF);
}
__device__ __forceinline__ float sigf(float x) { return __builtin_amdgcn_rcpf(1.f + __expf(-x)); }
__device__ __forceinline__ float tanh_fast(float x) { return 1.f - 2.f * __builtin_amdgcn_rcpf(1.f + __expf(2.f * x)); }

// ---------------- prep kernels ----------------
// Combined fp8 weight matrix W[4096][1152], rows reordered:
// orig n = g*HID + j  ->  new n = (j>>5)*128 + g*32 + (j&31)
__global__ __launch_bounds__(256) void prep_w(const float* __restrict__ W_hh, const float* __restrict__ W_ih,
                                              u8* __restrict__ W) {
    int newn = blockIdx.x;
    int nbk = newn >> 7, rem = newn & 127, g = rem >> 5, jl = rem & 31;
    int orig = g * HID + nbk * 32 + jl;
    u8* dst = W + (size_t)newn * KTOT;
    const float* src = W_hh + (size_t)orig * HID;
    const float* src2 = W_ih + (size_t)orig * (2 * FEAT);
    for (int k4 = threadIdx.x; k4 < KTOT / 4; k4 += 256) {
        int k = k4 * 4;
        float f0, f1, f2, f3;
        if (k < HID) {
            f0 = src[k]; f1 = src[k + 1]; f2 = src[k + 2]; f3 = src[k + 3];
        } else {
            int q = k - HID;
            f0 = (q     < 2 * FEAT) ? src2[q]     : 0.f;
            f1 = (q + 1 < 2 * FEAT) ? src2[q + 1] : 0.f;
            f2 = (q + 2 < 2 * FEAT) ? src2[q + 2] : 0.f;
            f3 = (q + 3 < 2 * FEAT) ? src2[q + 3] : 0.f;
        }
        *(unsigned*)(dst + k) = pk4_fp8(f0, f1, f2, f3);
    }
}

__global__ __launch_bounds__(256) void prep_bias(const float* __restrict__ b_ih, const float* __restrict__ b_hh,
                                                 float* __restrict__ bias_r) {
    int newn = blockIdx.x * 256 + threadIdx.x;
    int nbk = newn >> 7, rem = newn & 127, g = rem >> 5, jl = rem & 31;
    int orig = g * HID + nbk * 32 + jl;
    bias_r[newn] = b_ih[orig] + b_hh[orig];
}

// tdWtb[j][f] bf16, [1024][64], f>=35 zero.
__global__ __launch_bounds__(256) void prep_tdwtb(const float* __restrict__ td_W, u16* __restrict__ tdWtb) {
    int idx = blockIdx.x * 256 + threadIdx.x;
    int row = idx >> 6, f = idx & 63;
    tdWtb[idx] = (f < FEAT) ? f2b(td_W[(size_t)row * FEAT + f]) : (u16)0;
}

// regW8[f][k] fp8, [48][1024], f>=35 zero.
__global__ __launch_bounds__(256) void prep_regw8(const float* __restrict__ reg_W, u8* __restrict__ regW8) {
    int row = blockIdx.x;           // 48
    int k = threadIdx.x * 4;        // 1024
    float f0 = 0.f, f1 = 0.f, f2 = 0.f, f3 = 0.f;
    if (row < FEAT) {
        const float* s = reg_W + (size_t)row * HID + k;
        f0 = s[0]; f1 = s[1]; f2 = s[2]; f3 = s[3];
    }
    *(unsigned*)(regW8 + (size_t)row * 1024 + k) = pk4_fp8(f0, f1, f2, f3);
}

// ---------------- stepR: regression + x_c + loss + gamma(t+1) ----------------
// R4 change: gamma results staged in LDS (g_sh, row stride 1032 u16 -> 16B-aligned
// rows, ~2-way banked) and flushed to gbuf with coalesced u16x8 stores, replacing
// 64 scattered 2B stores/lane (2KB row stride) that dominated stepR's write path.
// X tail pad zeros now pre-set once at launch (memset of both buffers).
__global__ __launch_bounds__(256) void stepR(const float* __restrict__ values, const float* __restrict__ masks,
                                             const float* __restrict__ deltas, const u16* __restrict__ tdWtb,
                                             const float* __restrict__ td_b, const u8* __restrict__ regW8,
                                             const float* __restrict__ reg_b, u8* __restrict__ X,
                                             u16* __restrict__ gbuf, float* __restrict__ imput,
                                             float* __restrict__ xnum_part, float* __restrict__ xden_part,
                                             int t, int gflag) {
    __shared__ u16 d_sh[16 * 64];          // bf16 d(t+1), 16B-chunk XOR swizzled per row
    __shared__ float x_sh[16 * 35], m_sh[16 * 35];
    __shared__ float xhp[4][16][49];       // per-wave regression partials (padded)
    __shared__ float redbuf[8];
    __shared__ u16 g_sh[16 * 1032];        // gamma tile, padded row stride

    int tid = threadIdx.x;
    int wave = tid >> 6, lane = tid & 63;
    int cl = lane & 15, quad = lane >> 4;
    int b0 = blockIdx.x * 16;

    for (int i = tid; i < 16 * 35; i += 256) {
        int b = i / 35, f = i - b * 35;
        size_t g = ((size_t)(b0 + b) * TLEN + t) * FEAT + f;
        x_sh[i] = values[g];
        m_sh[i] = masks[g];
    }
    if (gflag && tid < 128) {
        int b = tid >> 3, cch = tid & 7;
        const float* drow = deltas + ((size_t)(b0 + b) * TLEN + (t + 1)) * FEAT;
        u16x8 tv;
        #pragma unroll
        for (int k = 0; k < 8; ++k) {
            int f = cch * 8 + k;
            tv[k] = (f < FEAT) ? f2b(drow[f]) : (u16)0;
        }
        int csw = cch ^ (b & 7);
        *(u16x8*)(d_sh + b * 64 + csw * 8) = tv;
    }
    __syncthreads();

    // ---- regression via MX-fp8 MFMA (K split: wave covers K [wave*256, +256)) ----
    f32x4 racc[3];
    #pragma unroll
    for (int nt = 0; nt < 3; ++nt) racc[nt] = (f32x4){0.f, 0.f, 0.f, 0.f};
    const u8* xrow = X + (size_t)(b0 + cl) * KTOT + wave * 256;
    #pragma unroll
    for (int it = 0; it < 2; ++it) {
        v8i av = *(const v8i*)(xrow + it * 128 + quad * 32);
        #pragma unroll
        for (int nt = 0; nt < 3; ++nt) {
            v8i bvv = *(const v8i*)(regW8 + (size_t)(nt * 16 + cl) * 1024 + wave * 256 + it * 128 + quad * 32);
            racc[nt] = __builtin_amdgcn_mfma_scale_f32_16x16x128_f8f6f4(
                av, bvv, racc[nt], 0, 0, 0, SCALE1, 0, SCALE1);
        }
    }
    #pragma unroll
    for (int nt = 0; nt < 3; ++nt)
        #pragma unroll
        for (int r = 0; r < 4; ++r)
            xhp[wave][quad * 4 + r][nt * 16 + cl] = racc[nt][r];

    // ---- gamma MFMA (bf16): wave covers j-tiles [wave*16, wave*16+16) ----
    if (gflag) {
        int swc0 = quad ^ (cl & 7);
        int swc1 = (4 + quad) ^ (cl & 7);
        bf16x8 a0 = *(const bf16x8*)(d_sh + cl * 64 + swc0 * 8);
        bf16x8 a1 = *(const bf16x8*)(d_sh + cl * 64 + swc1 * 8);
        #pragma unroll 4
        for (int jt2 = 0; jt2 < 16; ++jt2) {
            int jt = wave * 16 + jt2;
            const u16* tw = tdWtb + (size_t)(jt * 16 + cl) * 64;
            bf16x8 b0v = *(const bf16x8*)(tw + quad * 8);
            bf16x8 b1v = *(const bf16x8*)(tw + 32 + quad * 8);
            f32x4 g4 = (f32x4){0.f, 0.f, 0.f, 0.f};
            g4 = __builtin_amdgcn_mfma_f32_16x16x32_bf16(a0, b0v, g4, 0, 0, 0);
            g4 = __builtin_amdgcn_mfma_f32_16x16x32_bf16(a1, b1v, g4, 0, 0, 0);
            float4 tb = *(const float4*)(td_b + jt * 16 + quad * 4);
            float tbv[4] = {tb.x, tb.y, tb.z, tb.w};
            #pragma unroll
            for (int r = 0; r < 4; ++r) {
                u16 gam = f2b(__expf(-fmaxf(g4[r] + tbv[r], 0.f)));
                g_sh[(quad * 4 + r) * 1032 + jt * 16 + cl] = gam;
            }
        }
    }
    __syncthreads();

    // ---- epilogue: x_c, imputations, X tail (fp8), loss partials, gbuf flush ----
    if (gflag) {
        for (int i = tid; i < 16 * 128; i += 256) {
            int row = i >> 7, col = (i & 127) * 8;
            *(u16x8*)(gbuf + (size_t)(b0 + row) * HID + col) = *(const u16x8*)(g_sh + row * 1032 + col);
        }
    }
    float lossN = 0.f, lossD = 0.f;
    for (int i = tid; i < 16 * 35; i += 256) {
        int b = i / 35, f = i - b * 35;
        float xh = xhp[0][b][f] + xhp[1][b][f] + xhp[2][b][f] + xhp[3][b][f] + reg_b[f];
        float xv = x_sh[i], mv = m_sh[i];
        float xc = mv * xv + (1.f - mv) * xh;
        imput[((size_t)(b0 + b) * TLEN + t) * FEAT + f] = xc;
        u8* Xr = X + (size_t)(b0 + b) * KTOT;
        Xr[HID + f] = f2e4m3(xc);
        Xr[HID + FEAT + f] = f2e4m3(mv);
        lossN += fabsf(xv - xh) * mv;
        lossD += mv;
    }
    #pragma unroll
    for (int off = 32; off; off >>= 1) {
        lossN += __shfl_down(lossN, off);
        lossD += __shfl_down(lossD, off);
    }
    if (lane == 0) { redbuf[wave] = lossN; redbuf[4 + wave] = lossD; }
    __syncthreads();
    if (tid == 0) {
        xnum_part[t * 256 + blockIdx.x] = redbuf[0] + redbuf[1] + redbuf[2] + redbuf[3];
        xden_part[t * 256 + blockIdx.x] = redbuf[4] + redbuf[5] + redbuf[6] + redbuf[7];
    }
}

// ---------------- stepB: MX-fp8 MFMA gates GEMM + fused LSTM cell + decay for t+1 ----------------
// EXACT R0-baseline body (40.3us, VGPR 112 arch + AGPR acc, no spill). R1-R3 lesson:
// any restructuring of this K-loop (8 waves, phase barriers, prefetch-before-compute)
// makes the allocator abandon the AGPR split and spill ~70 regs/iter (300-500MB of
// scratch traffic). Only the block->tile mapping changed (bijective 4mb x 16nb per
// XCD -> 1.2MB X + 2.4MB W per XCD L2).
__global__ __launch_bounds__(256, 2) void stepB(const u8* __restrict__ X, const u8* __restrict__ W,
                                                const float* __restrict__ bias_r, const u16* __restrict__ gbuf,
                                                u16* __restrict__ c, u8* __restrict__ Xn,
                                                u16* __restrict__ h, int last) {
    __shared__ u8 As[256 * 128];
    __shared__ u8 Bs[128 * 128];
    int bid = blockIdx.x;
    int xcd = bid & 7, r0 = bid >> 3;            // r0 in [0,64)
    int mb = (xcd >> 1) * 4 + (r0 & 3);          // [0,16)
    int nb = (xcd & 1) * 16 + (r0 >> 2);         // [0,32)
    int tid = threadIdx.x;
    int wave = tid >> 6, lane = tid & 63;
    int lrow = lane >> 3;            // 0..7 row within 8-row staging group
    int gchunk = (lane & 7) ^ lrow;  // swizzled global 16B-chunk to fetch
    int cl = lane & 15, quad = lane >> 4;
    int c7 = cl & 7;

    f32x4 acc[4][8];
    #pragma unroll
    for (int mi = 0; mi < 4; ++mi)
        #pragma unroll
        for (int ni = 0; ni < 8; ++ni) acc[mi][ni] = (f32x4){0.f, 0.f, 0.f, 0.f};

    for (int kt = 0; kt < KTOT / 128; ++kt) {     // 9 iterations
        __syncthreads();
        #pragma unroll
        for (int it = 0; it < 8; ++it) {
            int rl = wave * 64 + it * 8;          // A rows [wave*64 .. +64)
            const u8* ga = X + (size_t)(mb * 256 + rl + lrow) * KTOT + kt * 128 + gchunk * 16;
            __builtin_amdgcn_global_load_lds((const __attribute__((address_space(1))) void*)ga,
                                             (__attribute__((address_space(3))) void*)(As + rl * 128),
                                             16, 0, 0);
        }
        #pragma unroll
        for (int it = 0; it < 4; ++it) {
            int rl = wave * 32 + it * 8;          // B rows [wave*32 .. +32)
            const u8* gb = W + (size_t)(nb * 128 + rl + lrow) * KTOT + kt * 128 + gchunk * 16;
            __builtin_amdgcn_global_load_lds((const __attribute__((address_space(1))) void*)gb,
                                             (__attribute__((address_space(3))) void*)(Bs + rl * 128),
                                             16, 0, 0);
        }
        __syncthreads();

        v8i av[4];
        #pragma unroll
        for (int mi = 0; mi < 4; ++mi) {
            const u8* base = As + (wave * 64 + mi * 16 + cl) * 128;
            v4i lo = *(const v4i*)(base + (((2 * quad) ^ c7) << 4));
            v4i hi = *(const v4i*)(base + (((2 * quad + 1) ^ c7) << 4));
            av[mi] = (v8i){lo[0], lo[1], lo[2], lo[3], hi[0], hi[1], hi[2], hi[3]};
        }
        #pragma unroll
        for (int ni = 0; ni < 8; ++ni) {
            const u8* base = Bs + (ni * 16 + cl) * 128;
            v4i lo = *(const v4i*)(base + (((2 * quad) ^ c7) << 4));
            v4i hi = *(const v4i*)(base + (((2 * quad + 1) ^ c7) << 4));
            v8i bvv = (v8i){lo[0], lo[1], lo[2], lo[3], hi[0], hi[1], hi[2], hi[3]};
            #pragma unroll
            for (int mi = 0; mi < 4; ++mi)
                acc[mi][ni] = __builtin_amdgcn_mfma_scale_f32_16x16x128_f8f6f4(
                    av[mi], bvv, acc[mi][ni], 0, 0, 0, SCALE1, 0, SCALE1);
        }
    }

    // fused LSTM epilogue; for t<47 write X_hdec(t+1) = h*gamma(t+1) in fp8, for t=47 write h bf16.
    #pragma unroll
    for (int mi = 0; mi < 4; ++mi) {
        #pragma unroll
        for (int r = 0; r < 4; ++r) {
            int b = mb * 256 + wave * 64 + mi * 16 + quad * 4 + r;
            #pragma unroll
            for (int jh = 0; jh < 2; ++jh) {
                int jl = jh * 16 + cl;
                int j = nb * 32 + jl;
                float iv = acc[mi][jh + 0][r] + bias_r[nb * 128 + jl];
                float fv = acc[mi][jh + 2][r] + bias_r[nb * 128 + 32 + jl];
                float gg = acc[mi][jh + 4][r] + bias_r[nb * 128 + 64 + jl];
                float ov = acc[mi][jh + 6][r] + bias_r[nb * 128 + 96 + jl];
                iv = sigf(iv); fv = sigf(fv); ov = sigf(ov); gg = tanh_fast(gg);
                size_t idx = (size_t)b * HID + j;
                float cn = fv * b2f(c[idx]) + iv * gg;
                c[idx] = f2b(cn);
                float hn = ov * tanh_fast(cn);
                if (last) {
                    h[idx] = f2b(hn);
                } else {
                    Xn[(size_t)b * KTOT + j] = f2e4m3(hn * b2f(gbuf[idx]));
                }
            }
        }
    }
}

// ---------------- final kernels (atomic-free) ----------------
__global__ __launch_bounds__(256) void finalY(const u16* __restrict__ h, const float* __restrict__ out_W,
                                              const float* __restrict__ out_b, const float* __restrict__ labels,
                                              const float* __restrict__ is_train, float* __restrict__ preds,
                                              float* __restrict__ bce_part, float* __restrict__ it_part) {
    __shared__ float wbuf[8];
    int tid = threadIdx.x;
    int wave = tid >> 6, lane = tid & 63;
    int cl = lane & 15, quad = lane >> 4;
    int b = blockIdx.x * 16 + wave * 4 + quad;
    const u16x8* hp = (const u16x8*)(h + (size_t)b * HID + cl * 64);
    const float4* wp = (const float4*)(out_W + cl * 64);
    float s = 0.f;
    #pragma unroll
    for (int i = 0; i < 8; ++i) {
        u16x8 hv = hp[i];
        float4 wa = wp[2 * i], wb = wp[2 * i + 1];
        s += b2f(hv[0]) * wa.x + b2f(hv[1]) * wa.y + b2f(hv[2]) * wa.z + b2f(hv[3]) * wa.w
           + b2f(hv[4]) * wb.x + b2f(hv[5]) * wb.y + b2f(hv[6]) * wb.z + b2f(hv[7]) * wb.w;
    }
    s += __shfl_down(s, 8, 16);
    s += __shfl_down(s, 4, 16);
    s += __shfl_down(s, 2, 16);
    s += __shfl_down(s, 1, 16);
    float v1 = 0.f, v2 = 0.f;
    if (cl == 0) {
        float y = s + out_b[0];
        preds[b] = 1.f / (1.f + expf(-y));
        float lab = labels[b], it = is_train[b];
        float mv = fmaxf(-y, 0.f);
        float bce = y - y * lab + mv + logf(expf(-mv) + expf(-y - mv));
        v1 = bce * it; v2 = it;
    }
    v1 += __shfl_xor(v1, 16); v2 += __shfl_xor(v2, 16);
    v1 += __shfl_xor(v1, 32); v2 += __shfl_xor(v2, 32);
    if (lane == 0) { wbuf[wave] = v1; wbuf[4 + wave] = v2; }
    __syncthreads();
    if (tid == 0) {
        bce_part[blockIdx.x] = wbuf[0] + wbuf[1] + wbuf[2] + wbuf[3];
        it_part[blockIdx.x]  = wbuf[4] + wbuf[5] + wbuf[6] + wbuf[7];
    }
}

__global__ __launch_bounds__(256) void finalZ(const float* __restrict__ xnum, const float* __restrict__ xden,
                                              const float* __restrict__ bce_part, const float* __restrict__ it_part,
                                              float* __restrict__ out0) {
    __shared__ float wbuf[12];
    int tid = threadIdx.x, wave = tid >> 6, lane = tid & 63;
    float bs = bce_part[tid], is = it_part[tid];
    #pragma unroll
    for (int off = 32; off; off >>= 1) { bs += __shfl_down(bs, off); is += __shfl_down(is, off); }
    float xl = 0.f;
    for (int t = wave; t < TLEN; t += 4) {
        float n = 0.f, d = 0.f;
        #pragma unroll
        for (int i = 0; i < 4; ++i) { n += xnum[t * 256 + lane + i * 64]; d += xden[t * 256 + lane + i * 64]; }
        #pragma unroll
        for (int off = 32; off; off >>= 1) { n += __shfl_down(n, off); d += __shfl_down(d, off); }
        if (lane == 0) xl += n / (d + 1e-5f);
    }
    if (lane == 0) { wbuf[wave] = xl; wbuf[4 + wave] = bs; wbuf[8 + wave] = is; }
    __syncthreads();
    if (tid == 0) {
        float XL = wbuf[0] + wbuf[1] + wbuf[2] + wbuf[3];
        float BS = wbuf[4] + wbuf[5] + wbuf[6] + wbuf[7];
        float IS = wbuf[8] + wbuf[9] + wbuf[10] + wbuf[11];
        out0[0] = 0.3f * XL + BS / (IS + 1e-5f);
    }
}

// ---------------- launch ----------------
extern "C" void kernel_launch(void* const* d_in, const int* in_sizes, int n_in,
                              void* d_out, int out_size, void* d_ws, size_t ws_size,
                              hipStream_t stream) {
    const float* values   = (const float*)d_in[0];
    const float* masks    = (const float*)d_in[1];
    const float* deltas   = (const float*)d_in[2];
    const float* labels   = (const float*)d_in[3];
    const float* is_train = (const float*)d_in[4];
    const float* td_W     = (const float*)d_in[5];
    const float* td_b     = (const float*)d_in[6];
    const float* W_ih     = (const float*)d_in[7];
    const float* W_hh     = (const float*)d_in[8];
    const float* b_ih     = (const float*)d_in[9];
    const float* b_hh     = (const float*)d_in[10];
    const float* reg_W    = (const float*)d_in[11];
    const float* reg_b    = (const float*)d_in[12];
    const float* out_W    = (const float*)d_in[13];
    const float* out_b    = (const float*)d_in[14];

    float* out = (float*)d_out;

    // workspace (bytes): c bf16[BH] | h bf16[BH] | gbuf bf16[BH] | Xa u8[B*KTOT] | Xb u8[B*KTOT]
    //                    | W8 u8[H4*KTOT] | bias f32[H4] | tdWtb bf16[64K] | regW8 u8[48*1024] | parts
    u16*   c      = (u16*)d_ws;
    u16*   h      = c + BH;
    u16*   gbuf   = h + BH;
    u8*    Xa     = (u8*)(gbuf + BH);
    u8*    Xb     = Xa + (size_t)BDIM * KTOT;
    u8*    W8     = Xb + (size_t)BDIM * KTOT;
    float* bias_r = (float*)(W8 + (size_t)H4 * KTOT);
    u16*   tdWtb  = (u16*)(bias_r + H4);
    u8*    regW8  = (u8*)(tdWtb + 1024 * 64);
    float* xnum_part = (float*)(regW8 + 48 * 1024);
    float* xden_part = xnum_part + TLEN * 256;
    float* bce_part  = xden_part + TLEN * 256;
    float* it_part   = bce_part + 256;

    hipMemsetAsync(c, 0, BH * sizeof(u16), stream);                 // c = 0
    hipMemsetAsync(Xa, 0, (size_t)BDIM * KTOT, stream);             // X_hdec(0) = 0 + pad zeros
    hipMemsetAsync(Xb, 0, (size_t)BDIM * KTOT, stream);             // pad zeros (stay zero forever)

    prep_w<<<H4, 256, 0, stream>>>(W_hh, W_ih, W8);
    prep_bias<<<H4 / 256, 256, 0, stream>>>(b_ih, b_hh, bias_r);
    prep_tdwtb<<<256, 256, 0, stream>>>(td_W, tdWtb);
    prep_regw8<<<48, 256, 0, stream>>>(reg_W, regW8);

    float* imput = out + 1 + BDIM;
    for (int t = 0; t < TLEN; t++) {
        u8* cur = (t & 1) ? Xb : Xa;
        u8* nxt = (t & 1) ? Xa : Xb;
        stepR<<<BDIM / 16, 256, 0, stream>>>(values, masks, deltas, tdWtb, td_b, regW8, reg_b,
                                             cur, gbuf, imput, xnum_part, xden_part, t, t < TLEN - 1);
        stepB<<<512, 256, 0, stream>>>(cur, W8, bias_r, gbuf, c, nxt, h, t == TLEN - 1);
    }
    finalY<<<BDIM / 16, 256, 0, stream>>>(h, out_W, out_b, labels, is_train, out + 1, bce_part, it_part);
    finalZ<<<1, 256, 0, stream>>>(xnum_part, xden_part, bce_part, it_part, out);
}

// Round 7
// 2079.734 us; speedup vs baseline: 6.9778x; 1.2820x over previous
//
#include <hip/hip_runtime.h>
#include <math.h>

// Problem constants
#define BDIM 4096
#define TLEN 48
#define FEAT 35
#define HID 1024
#define H4 4096
#define KTOT 1152      // 1024 (hh) + 128 (ih, 70 real + 58 zero pad)

#define BH ((size_t)BDIM * HID)

typedef unsigned short u16;
typedef unsigned char u8;
typedef __bf16 bf16x8 __attribute__((ext_vector_type(8)));
typedef float f32x4 __attribute__((ext_vector_type(4)));
typedef u16 u16x8 __attribute__((ext_vector_type(8)));
typedef int v8i __attribute__((ext_vector_type(8)));
typedef int v4i __attribute__((ext_vector_type(4)));

#define SCALE1 0x7F7F7F7F   // E8M0 scale = 1.0 in every byte

__device__ __forceinline__ float b2f(u16 u) {
    union { float f; unsigned i; } v; v.i = ((unsigned)u) << 16; return v.f;
}
__device__ __forceinline__ u16 f2b(float f) {
    union { float f; unsigned i; } v; v.f = f;
    unsigned r = v.i + 0x7FFF + ((v.i >> 16) & 1);
    return (u16)(r >> 16);
}
__device__ __forceinline__ unsigned pk4_fp8(float a, float b, float c, float d) {
    int lo = __builtin_amdgcn_cvt_pk_fp8_f32(a, b, 0, false);
    int hi = __builtin_amdgcn_cvt_pk_fp8_f32(c, d, lo, true);
    return (unsigned)hi;
}
__device__ __forceinline__ u8 f2e4m3(float f) {
    return (u8)(__builtin_amdgcn_cvt_pk_fp8_f32(f, 0.f, 0, false) & 0xFF);
}
__device__ __forceinline__ float sigf(float x) { return __builtin_amdgcn_rcpf(1.f + __expf(-x)); }
__device__ __forceinline__ float tanh_fast(float x) { return 1.f - 2.f * __builtin_amdgcn_rcpf(1.f + __expf(2.f * x)); }

// ---------------- prep kernels ----------------
// Combined fp8 weight matrix W[4096][1152], rows reordered:
// orig n = g*HID + j  ->  new n = (j>>5)*128 + g*32 + (j&31)
__global__ __launch_bounds__(256) void prep_w(const float* __restrict__ W_hh, const float* __restrict__ W_ih,
                                              u8* __restrict__ W) {
    int newn = blockIdx.x;
    int nbk = newn >> 7, rem = newn & 127, g = rem >> 5, jl = rem & 31;
    int orig = g * HID + nbk * 32 + jl;
    u8* dst = W + (size_t)newn * KTOT;
    const float* src = W_hh + (size_t)orig * HID;
    const float* src2 = W_ih + (size_t)orig * (2 * FEAT);
    for (int k4 = threadIdx.x; k4 < KTOT / 4; k4 += 256) {
        int k = k4 * 4;
        float f0, f1, f2, f3;
        if (k < HID) {
            f0 = src[k]; f1 = src[k + 1]; f2 = src[k + 2]; f3 = src[k + 3];
        } else {
            int q = k - HID;
            f0 = (q     < 2 * FEAT) ? src2[q]     : 0.f;
            f1 = (q + 1 < 2 * FEAT) ? src2[q + 1] : 0.f;
            f2 = (q + 2 < 2 * FEAT) ? src2[q + 2] : 0.f;
            f3 = (q + 3 < 2 * FEAT) ? src2[q + 3] : 0.f;
        }
        *(unsigned*)(dst + k) = pk4_fp8(f0, f1, f2, f3);
    }
}

__global__ __launch_bounds__(256) void prep_bias(const float* __restrict__ b_ih, const float* __restrict__ b_hh,
                                                 float* __restrict__ bias_r) {
    int newn = blockIdx.x * 256 + threadIdx.x;
    int nbk = newn >> 7, rem = newn & 127, g = rem >> 5, jl = rem & 31;
    int orig = g * HID + nbk * 32 + jl;
    bias_r[newn] = b_ih[orig] + b_hh[orig];
}

// tdWtb[j][f] bf16, [1024][64], f>=35 zero.
__global__ __launch_bounds__(256) void prep_tdwtb(const float* __restrict__ td_W, u16* __restrict__ tdWtb) {
    int idx = blockIdx.x * 256 + threadIdx.x;
    int row = idx >> 6, f = idx & 63;
    tdWtb[idx] = (f < FEAT) ? f2b(td_W[(size_t)row * FEAT + f]) : (u16)0;
}

// regW8[f][k] fp8, [48][1024], f>=35 zero.
__global__ __launch_bounds__(256) void prep_regw8(const float* __restrict__ reg_W, u8* __restrict__ regW8) {
    int row = blockIdx.x;           // 48
    int k = threadIdx.x * 4;        // 1024
    float f0 = 0.f, f1 = 0.f, f2 = 0.f, f3 = 0.f;
    if (row < FEAT) {
        const float* s = reg_W + (size_t)row * HID + k;
        f0 = s[0]; f1 = s[1]; f2 = s[2]; f3 = s[3];
    }
    *(unsigned*)(regW8 + (size_t)row * 1024 + k) = pk4_fp8(f0, f1, f2, f3);
}

// dbuf[t][b][64] bf16 (f>=35 zero), linear layout. Row = 128B. One-time conversion of
// deltas so stepB can global_load_lds-stage its [256][64] slice per block.
__global__ __launch_bounds__(256) void prep_dbuf(const float* __restrict__ deltas, u16* __restrict__ dbuf) {
    int bid = blockIdx.x;                 // 48 * 128
    int t = bid >> 7, rc = bid & 127;
    int row = rc * 32 + (threadIdx.x >> 3), cch = threadIdx.x & 7;
    const float* dr = deltas + ((size_t)row * TLEN + t) * FEAT;
    u16x8 tv;
    #pragma unroll
    for (int k = 0; k < 8; ++k) {
        int f = cch * 8 + k;
        tv[k] = (f < FEAT) ? f2b(dr[f]) : (u16)0;
    }
    *(u16x8*)(dbuf + ((size_t)t * BDIM + row) * 64 + cch * 8) = tv;
}

// ---------------- stepR: regression + x_c + loss (gamma moved into stepB) ----------------
// R6: gamma/gbuf removed entirely (gamma depends only on deltas -> computed in stepB's
// epilogue). Block->rows remap is XCD-aware: rows mb*256.. were written by stepB(t-1)
// blocks on XCDs {2*(mb>>2), 2*(mb>>2)+1}; land this block on one of those XCDs.
__global__ __launch_bounds__(256) void stepR(const float* __restrict__ values, const float* __restrict__ masks,
                                             const u8* __restrict__ regW8, const float* __restrict__ reg_b,
                                             u8* __restrict__ X, float* __restrict__ imput,
                                             float* __restrict__ xnum_part, float* __restrict__ xden_part,
                                             int t) {
    __shared__ float x_sh[16 * 35], m_sh[16 * 35];
    __shared__ float xhp[4][16][49];       // per-wave regression partials (padded)
    __shared__ float redbuf[8];

    int tid = threadIdx.x;
    int wave = tid >> 6, lane = tid & 63;
    int cl = lane & 15, quad = lane >> 4;
    int bid = blockIdx.x;
    int xs = bid & 7, qs = bid >> 3;       // bijective XCD-aware remap
    int b0 = (4 * (xs >> 1) + (qs & 3)) * 256 + ((xs & 1) * 8 + (qs >> 2)) * 16;

    for (int i = tid; i < 16 * 35; i += 256) {
        int b = i / 35, f = i - b * 35;
        size_t g = ((size_t)(b0 + b) * TLEN + t) * FEAT + f;
        x_sh[i] = values[g];
        m_sh[i] = masks[g];
    }
    __syncthreads();

    // ---- regression via MX-fp8 MFMA (K split: wave covers K [wave*256, +256)) ----
    f32x4 racc[3];
    #pragma unroll
    for (int nt = 0; nt < 3; ++nt) racc[nt] = (f32x4){0.f, 0.f, 0.f, 0.f};
    const u8* xrow = X + (size_t)(b0 + cl) * KTOT + wave * 256;
    #pragma unroll
    for (int it = 0; it < 2; ++it) {
        v8i av = *(const v8i*)(xrow + it * 128 + quad * 32);
        #pragma unroll
        for (int nt = 0; nt < 3; ++nt) {
            v8i bvv = *(const v8i*)(regW8 + (size_t)(nt * 16 + cl) * 1024 + wave * 256 + it * 128 + quad * 32);
            racc[nt] = __builtin_amdgcn_mfma_scale_f32_16x16x128_f8f6f4(
                av, bvv, racc[nt], 0, 0, 0, SCALE1, 0, SCALE1);
        }
    }
    #pragma unroll
    for (int nt = 0; nt < 3; ++nt)
        #pragma unroll
        for (int r = 0; r < 4; ++r)
            xhp[wave][quad * 4 + r][nt * 16 + cl] = racc[nt][r];
    __syncthreads();

    // ---- epilogue: x_c, imputations, X tail (fp8), loss partials ----
    float lossN = 0.f, lossD = 0.f;
    for (int i = tid; i < 16 * 35; i += 256) {
        int b = i / 35, f = i - b * 35;
        float xh = xhp[0][b][f] + xhp[1][b][f] + xhp[2][b][f] + xhp[3][b][f] + reg_b[f];
        float xv = x_sh[i], mv = m_sh[i];
        float xc = mv * xv + (1.f - mv) * xh;
        imput[((size_t)(b0 + b) * TLEN + t) * FEAT + f] = xc;
        u8* Xr = X + (size_t)(b0 + b) * KTOT;
        Xr[HID + f] = f2e4m3(xc);
        Xr[HID + FEAT + f] = f2e4m3(mv);
        lossN += fabsf(xv - xh) * mv;
        lossD += mv;
    }
    #pragma unroll
    for (int off = 32; off; off >>= 1) {
        lossN += __shfl_down(lossN, off);
        lossD += __shfl_down(lossD, off);
    }
    if (lane == 0) { redbuf[wave] = lossN; redbuf[4 + wave] = lossD; }
    __syncthreads();
    if (tid == 0) {
        xnum_part[t * 256 + blockIdx.x] = redbuf[0] + redbuf[1] + redbuf[2] + redbuf[3];
        xden_part[t * 256 + blockIdx.x] = redbuf[4] + redbuf[5] + redbuf[6] + redbuf[7];
    }
}

// ---------------- stepB: MX-fp8 MFMA gates GEMM + fused LSTM cell + inline gamma(t+1) ----------------
// K-loop body is the EXACT proven baseline (40.3us, VGPR 112 arch + AGPR acc, no spill).
// R6 addition is entirely POST-loop: restage As (32KB, exactly fits) with dbuf(t+1)
// [256 rows][64] bf16 via the same global_load_lds+XOR pattern, then per mi-tile compute
// gamma(t+1) with 4 bf16 MFMAs (C-layout row=quad*4+r(b), col=cl(j) == acc layout) and
// fuse into the LSTM epilogue. Kills the 16MB/t gbuf round-trip. td_b indexing replicates
// the verified stepR formula verbatim (tile_base + quad*4 + r) to keep numerics identical.
__global__ __launch_bounds__(256, 2) void stepB(const u8* __restrict__ X, const u8* __restrict__ W,
                                                const float* __restrict__ bias_r, const u16* __restrict__ tdWtb,
                                                const float* __restrict__ td_b, const u16* __restrict__ dbufT1,
                                                u16* __restrict__ c, u8* __restrict__ Xn,
                                                u16* __restrict__ h, int last) {
    __shared__ u8 As[256 * 128];
    __shared__ u8 Bs[128 * 128];
    int bid = blockIdx.x;
    int xcd = bid & 7, r0 = bid >> 3;            // r0 in [0,64)
    int mb = (xcd >> 1) * 4 + (r0 & 3);          // [0,16)
    int nb = (xcd & 1) * 16 + (r0 >> 2);         // [0,32)
    int tid = threadIdx.x;
    int wave = tid >> 6, lane = tid & 63;
    int lrow = lane >> 3;            // 0..7 row within 8-row staging group
    int gchunk = (lane & 7) ^ lrow;  // swizzled global 16B-chunk to fetch
    int cl = lane & 15, quad = lane >> 4;
    int c7 = cl & 15 & 7;

    f32x4 acc[4][8];
    #pragma unroll
    for (int mi = 0; mi < 4; ++mi)
        #pragma unroll
        for (int ni = 0; ni < 8; ++ni) acc[mi][ni] = (f32x4){0.f, 0.f, 0.f, 0.f};

    for (int kt = 0; kt < KTOT / 128; ++kt) {     // 9 iterations
        __syncthreads();
        #pragma unroll
        for (int it = 0; it < 8; ++it) {
            int rl = wave * 64 + it * 8;          // A rows [wave*64 .. +64)
            const u8* ga = X + (size_t)(mb * 256 + rl + lrow) * KTOT + kt * 128 + gchunk * 16;
            __builtin_amdgcn_global_load_lds((const __attribute__((address_space(1))) void*)ga,
                                             (__attribute__((address_space(3))) void*)(As + rl * 128),
                                             16, 0, 0);
        }
        #pragma unroll
        for (int it = 0; it < 4; ++it) {
            int rl = wave * 32 + it * 8;          // B rows [wave*32 .. +32)
            const u8* gb = W + (size_t)(nb * 128 + rl + lrow) * KTOT + kt * 128 + gchunk * 16;
            __builtin_amdgcn_global_load_lds((const __attribute__((address_space(1))) void*)gb,
                                             (__attribute__((address_space(3))) void*)(Bs + rl * 128),
                                             16, 0, 0);
        }
        __syncthreads();

        v8i av[4];
        #pragma unroll
        for (int mi = 0; mi < 4; ++mi) {
            const u8* base = As + (wave * 64 + mi * 16 + cl) * 128;
            v4i lo = *(const v4i*)(base + (((2 * quad) ^ c7) << 4));
            v4i hi = *(const v4i*)(base + (((2 * quad + 1) ^ c7) << 4));
            av[mi] = (v8i){lo[0], lo[1], lo[2], lo[3], hi[0], hi[1], hi[2], hi[3]};
        }
        #pragma unroll
        for (int ni = 0; ni < 8; ++ni) {
            const u8* base = Bs + (ni * 16 + cl) * 128;
            v4i lo = *(const v4i*)(base + (((2 * quad) ^ c7) << 4));
            v4i hi = *(const v4i*)(base + (((2 * quad + 1) ^ c7) << 4));
            v8i bvv = (v8i){lo[0], lo[1], lo[2], lo[3], hi[0], hi[1], hi[2], hi[3]};
            #pragma unroll
            for (int mi = 0; mi < 4; ++mi)
                acc[mi][ni] = __builtin_amdgcn_mfma_scale_f32_16x16x128_f8f6f4(
                    av[mi], bvv, acc[mi][ni], 0, 0, 0, SCALE1, 0, SCALE1);
        }
    }

    // ---- restage As with deltas(t+1) bf16 [256][64] for inline gamma ----
    if (!last) {
        __syncthreads();   // all waves done with K-loop LDS
        const u8* gd = (const u8*)dbufT1 + (size_t)(mb * 256) * 128;
        #pragma unroll
        for (int it = 0; it < 8; ++it) {
            int rl = wave * 64 + it * 8;
            __builtin_amdgcn_global_load_lds((const __attribute__((address_space(1))) void*)(gd + (size_t)(rl + lrow) * 128 + gchunk * 16),
                                             (__attribute__((address_space(3))) void*)(As + rl * 128),
                                             16, 0, 0);
        }
        __syncthreads();
    }

    // ---- fused epilogue: gamma(t+1) MFMA per mi-tile + LSTM cell ----
    const u16* Asw = (const u16*)As;
    int swc0 = quad ^ c7, swc1 = (4 + quad) ^ c7;
    #pragma unroll
    for (int mi = 0; mi < 4; ++mi) {
        float gam[2][4] = {{1.f, 1.f, 1.f, 1.f}, {1.f, 1.f, 1.f, 1.f}};
        if (!last) {
            int arow = wave * 64 + mi * 16 + cl;
            bf16x8 a0 = *(const bf16x8*)(Asw + arow * 64 + swc0 * 8);
            bf16x8 a1 = *(const bf16x8*)(Asw + arow * 64 + swc1 * 8);
            #pragma unroll
            for (int jh = 0; jh < 2; ++jh) {
                const u16* tw = tdWtb + (size_t)(nb * 32 + jh * 16 + cl) * 64;
                bf16x8 b0v = *(const bf16x8*)(tw + quad * 8);
                bf16x8 b1v = *(const bf16x8*)(tw + 32 + quad * 8);
                f32x4 g4 = (f32x4){0.f, 0.f, 0.f, 0.f};
                g4 = __builtin_amdgcn_mfma_f32_16x16x32_bf16(a0, b0v, g4, 0, 0, 0);
                g4 = __builtin_amdgcn_mfma_f32_16x16x32_bf16(a1, b1v, g4, 0, 0, 0);
                float4 tb = *(const float4*)(td_b + nb * 32 + jh * 16 + quad * 4);
                float tbv[4] = {tb.x, tb.y, tb.z, tb.w};
                #pragma unroll
                for (int r = 0; r < 4; ++r)
                    gam[jh][r] = __expf(-fmaxf(g4[r] + tbv[r], 0.f));
            }
        }
        #pragma unroll
        for (int r = 0; r < 4; ++r) {
            int b = mb * 256 + wave * 64 + mi * 16 + quad * 4 + r;
            #pragma unroll
            for (int jh = 0; jh < 2; ++jh) {
                int jl = jh * 16 + cl;
                int j = nb * 32 + jl;
                float iv = acc[mi][jh + 0][r] + bias_r[nb * 128 + jl];
                float fv = acc[mi][jh + 2][r] + bias_r[nb * 128 + 32 + jl];
                float gg = acc[mi][jh + 4][r] + bias_r[nb * 128 + 64 + jl];
                float ov = acc[mi][jh + 6][r] + bias_r[nb * 128 + 96 + jl];
                iv = sigf(iv); fv = sigf(fv); ov = sigf(ov); gg = tanh_fast(gg);
                size_t idx = (size_t)b * HID + j;
                float cn = fv * b2f(c[idx]) + iv * gg;
                c[idx] = f2b(cn);
                float hn = ov * tanh_fast(cn);
                if (last) {
                    h[idx] = f2b(hn);
                } else {
                    Xn[(size_t)b * KTOT + j] = f2e4m3(hn * gam[jh][r]);
                }
            }
        }
    }
}

// ---------------- final kernels (atomic-free) ----------------
__global__ __launch_bounds__(256) void finalY(const u16* __restrict__ h, const float* __restrict__ out_W,
                                              const float* __restrict__ out_b, const float* __restrict__ labels,
                                              const float* __restrict__ is_train, float* __restrict__ preds,
                                              float* __restrict__ bce_part, float* __restrict__ it_part) {
    __shared__ float wbuf[8];
    int tid = threadIdx.x;
    int wave = tid >> 6, lane = tid & 63;
    int cl = lane & 15, quad = lane >> 4;
    int b = blockIdx.x * 16 + wave * 4 + quad;
    const u16x8* hp = (const u16x8*)(h + (size_t)b * HID + cl * 64);
    const float4* wp = (const float4*)(out_W + cl * 64);
    float s = 0.f;
    #pragma unroll
    for (int i = 0; i < 8; ++i) {
        u16x8 hv = hp[i];
        float4 wa = wp[2 * i], wb = wp[2 * i + 1];
        s += b2f(hv[0]) * wa.x + b2f(hv[1]) * wa.y + b2f(hv[2]) * wa.z + b2f(hv[3]) * wa.w
           + b2f(hv[4]) * wb.x + b2f(hv[5]) * wb.y + b2f(hv[6]) * wb.z + b2f(hv[7]) * wb.w;
    }
    s += __shfl_down(s, 8, 16);
    s += __shfl_down(s, 4, 16);
    s += __shfl_down(s, 2, 16);
    s += __shfl_down(s, 1, 16);
    float v1 = 0.f, v2 = 0.f;
    if (cl == 0) {
        float y = s + out_b[0];
        preds[b] = 1.f / (1.f + expf(-y));
        float lab = labels[b], it = is_train[b];
        float mv = fmaxf(-y, 0.f);
        float bce = y - y * lab + mv + logf(expf(-mv) + expf(-y - mv));
        v1 = bce * it; v2 = it;
    }
    v1 += __shfl_xor(v1, 16); v2 += __shfl_xor(v2, 16);
    v1 += __shfl_xor(v1, 32); v2 += __shfl_xor(v2, 32);
    if (lane == 0) { wbuf[wave] = v1; wbuf[4 + wave] = v2; }
    __syncthreads();
    if (tid == 0) {
        bce_part[blockIdx.x] = wbuf[0] + wbuf[1] + wbuf[2] + wbuf[3];
        it_part[blockIdx.x]  = wbuf[4] + wbuf[5] + wbuf[6] + wbuf[7];
    }
}

__global__ __launch_bounds__(256) void finalZ(const float* __restrict__ xnum, const float* __restrict__ xden,
                                              const float* __restrict__ bce_part, const float* __restrict__ it_part,
                                              float* __restrict__ out0) {
    __shared__ float wbuf[12];
    int tid = threadIdx.x, wave = tid >> 6, lane = tid & 63;
    float bs = bce_part[tid], is = it_part[tid];
    #pragma unroll
    for (int off = 32; off; off >>= 1) { bs += __shfl_down(bs, off); is += __shfl_down(is, off); }
    float xl = 0.f;
    for (int t = wave; t < TLEN; t += 4) {
        float n = 0.f, d = 0.f;
        #pragma unroll
        for (int i = 0; i < 4; ++i) { n += xnum[t * 256 + lane + i * 64]; d += xden[t * 256 + lane + i * 64]; }
        #pragma unroll
        for (int off = 32; off; off >>= 1) { n += __shfl_down(n, off); d += __shfl_down(d, off); }
        if (lane == 0) xl += n / (d + 1e-5f);
    }
    if (lane == 0) { wbuf[wave] = xl; wbuf[4 + wave] = bs; wbuf[8 + wave] = is; }
    __syncthreads();
    if (tid == 0) {
        float XL = wbuf[0] + wbuf[1] + wbuf[2] + wbuf[3];
        float BS = wbuf[4] + wbuf[5] + wbuf[6] + wbuf[7];
        float IS = wbuf[8] + wbuf[9] + wbuf[10] + wbuf[11];
        out0[0] = 0.3f * XL + BS / (IS + 1e-5f);
    }
}

// ---------------- launch ----------------
extern "C" void kernel_launch(void* const* d_in, const int* in_sizes, int n_in,
                              void* d_out, int out_size, void* d_ws, size_t ws_size,
                              hipStream_t stream) {
    const float* values   = (const float*)d_in[0];
    const float* masks    = (const float*)d_in[1];
    const float* deltas   = (const float*)d_in[2];
    const float* labels   = (const float*)d_in[3];
    const float* is_train = (const float*)d_in[4];
    const float* td_W     = (const float*)d_in[5];
    const float* td_b     = (const float*)d_in[6];
    const float* W_ih     = (const float*)d_in[7];
    const float* W_hh     = (const float*)d_in[8];
    const float* b_ih     = (const float*)d_in[9];
    const float* b_hh     = (const float*)d_in[10];
    const float* reg_W    = (const float*)d_in[11];
    const float* reg_b    = (const float*)d_in[12];
    const float* out_W    = (const float*)d_in[13];
    const float* out_b    = (const float*)d_in[14];

    float* out = (float*)d_out;

    // workspace: c bf16[BH] | h bf16[BH] | dbuf bf16[48*4096*64] | Xa u8[B*KTOT] | Xb u8[B*KTOT]
    //            | W8 u8[H4*KTOT] | bias f32[H4] | tdWtb bf16[64K] | regW8 u8[48*1024] | parts
    u16*   c      = (u16*)d_ws;
    u16*   h      = c + BH;
    u16*   dbuf   = h + BH;
    u8*    Xa     = (u8*)(dbuf + (size_t)TLEN * BDIM * 64);
    u8*    Xb     = Xa + (size_t)BDIM * KTOT;
    u8*    W8     = Xb + (size_t)BDIM * KTOT;
    float* bias_r = (float*)(W8 + (size_t)H4 * KTOT);
    u16*   tdWtb  = (u16*)(bias_r + H4);
    u8*    regW8  = (u8*)(tdWtb + 1024 * 64);
    float* xnum_part = (float*)(regW8 + 48 * 1024);
    float* xden_part = xnum_part + TLEN * 256;
    float* bce_part  = xden_part + TLEN * 256;
    float* it_part   = bce_part + 256;

    hipMemsetAsync(c, 0, BH * sizeof(u16), stream);                 // c = 0
    hipMemsetAsync(Xa, 0, (size_t)BDIM * KTOT, stream);             // X_hdec(0) = 0 + pad zeros
    hipMemsetAsync(Xb, 0, (size_t)BDIM * KTOT, stream);             // pad zeros (stay zero forever)

    prep_w<<<H4, 256, 0, stream>>>(W_hh, W_ih, W8);
    prep_bias<<<H4 / 256, 256, 0, stream>>>(b_ih, b_hh, bias_r);
    prep_tdwtb<<<256, 256, 0, stream>>>(td_W, tdWtb);
    prep_regw8<<<48, 256, 0, stream>>>(reg_W, regW8);
    prep_dbuf<<<TLEN * 128, 256, 0, stream>>>(deltas, dbuf);

    float* imput = out + 1 + BDIM;
    for (int t = 0; t < TLEN; t++) {
        u8* cur = (t & 1) ? Xb : Xa;
        u8* nxt = (t & 1) ? Xa : Xb;
        const u16* dT1 = dbuf + (size_t)((t + 1 < TLEN) ? (t + 1) : 0) * BDIM * 64;
        stepR<<<BDIM / 16, 256, 0, stream>>>(values, masks, regW8, reg_b, cur, imput,
                                             xnum_part, xden_part, t);
        stepB<<<512, 256, 0, stream>>>(cur, W8, bias_r, tdWtb, td_b, dT1, c, nxt, h, t == TLEN - 1);
    }
    finalY<<<BDIM / 16, 256, 0, stream>>>(h, out_W, out_b, labels, is_train, out + 1, bce_part, it_part);
    finalZ<<<1, 256, 0, stream>>>(xnum_part, xden_part, bce_part, it_part, out);
}